// Round 3
// baseline (467.609 us; speedup 1.0000x reference)
//
#include <hip/hip_runtime.h>
#include <stdint.h>

// ---------------- problem constants ----------------
#define B2      192          // 16 * MAX_FRAMES
#define NTOK    50           // tokens per frame-batch
#define ROWS    9600         // B2 * NTOK
#define D_EMB   512
#define C_DIM   256
#define HD      128          // head dim
#define NSAMP   500
#define TOPKK   12
#define NSPA    48           // 50 - SEL_DIM

__device__ __forceinline__ float gelu_f(float x) {
    return 0.5f * x * (1.0f + erff(x * 0.7071067811865476f));
}

// ---------------- LayerNorm: one wave per row of 512 ----------------
__global__ __launch_bounds__(256) void ln_kernel(const float* __restrict__ x,
                                                 const float* __restrict__ g,
                                                 const float* __restrict__ b,
                                                 float* __restrict__ xn) {
    int row  = blockIdx.x * 4 + (threadIdx.x >> 6);
    int lane = threadIdx.x & 63;
    const float* rp = x + (size_t)row * D_EMB;
    float4 v0 = *(const float4*)(rp + lane * 8);
    float4 v1 = *(const float4*)(rp + lane * 8 + 4);
    float s  = v0.x + v0.y + v0.z + v0.w + v1.x + v1.y + v1.z + v1.w;
    float s2 = v0.x*v0.x + v0.y*v0.y + v0.z*v0.z + v0.w*v0.w
             + v1.x*v1.x + v1.y*v1.y + v1.z*v1.z + v1.w*v1.w;
#pragma unroll
    for (int off = 32; off; off >>= 1) {
        s  += __shfl_xor(s,  off);
        s2 += __shfl_xor(s2, off);
    }
    float mu  = s / 512.0f;
    float var = s2 / 512.0f - mu * mu;
    float inv = 1.0f / sqrtf(var + 1e-5f);
    float* op = xn + (size_t)row * D_EMB;
    const float* gp = g + lane * 8;
    const float* bp = b + lane * 8;
    float4 o0, o1;
    o0.x = (v0.x - mu) * inv * gp[0] + bp[0];
    o0.y = (v0.y - mu) * inv * gp[1] + bp[1];
    o0.z = (v0.z - mu) * inv * gp[2] + bp[2];
    o0.w = (v0.w - mu) * inv * gp[3] + bp[3];
    o1.x = (v1.x - mu) * inv * gp[4] + bp[4];
    o1.y = (v1.y - mu) * inv * gp[5] + bp[5];
    o1.z = (v1.z - mu) * inv * gp[6] + bp[6];
    o1.w = (v1.w - mu) * inv * gp[7] + bp[7];
    *(float4*)(op + lane * 8)     = o0;
    *(float4*)(op + lane * 8 + 4) = o1;
}

// ---------------- fp32 tiled GEMM: C[M,N] = act(A[M,K] @ W[K,N] + bias) ----------------
// BM=128 x BN=64 tile, 256 threads, 8x4 per thread (32 fma per 3 ds_read_b128).
// N%64==0, K%16==0 assumed; M guarded. bias (if non-null) indexed [(row/50)*N + col].
#define BM 128
#define BN 64
#define BK 16
__global__ __launch_bounds__(256) void gemm_f32(const float* __restrict__ A,
                                                const float* __restrict__ W,
                                                float* __restrict__ C,
                                                int M, int N, int K,
                                                const float* __restrict__ bias,
                                                int act) {
    __shared__ float As[BK][BM + 4];  // [k][m], padded (132 floats = 528 B rows)
    __shared__ float Ws[BK][BN];      // [k][n]
    int m0 = blockIdx.x * BM, n0 = blockIdx.y * BN;
    int tid = threadIdx.x;
    int tx = tid & 15;        // col group: 4 cols at tx*4
    int ty = tid >> 4;        // row group: 8 rows at ty*8
    int ar = tid >> 1;        // A-load row 0..127
    int ac = (tid & 1) * 8;   // A-load k-offset 0 or 8
    int wr = tid >> 4;        // W-load k row 0..15
    int wc = (tid & 15) * 4;  // W-load col
    int aRow = m0 + ar; if (aRow >= M) aRow = M - 1;   // clamp; epilogue guards
    const float* Arow = A + (size_t)aRow * K;
    float acc[8][4] = {};
    for (int k0 = 0; k0 < K; k0 += BK) {
        float4 a0 = *(const float4*)(Arow + k0 + ac);
        float4 a1 = *(const float4*)(Arow + k0 + ac + 4);
        float4 wv = *(const float4*)(W + (size_t)(k0 + wr) * N + n0 + wc);
        __syncthreads();
        As[ac + 0][ar] = a0.x; As[ac + 1][ar] = a0.y;
        As[ac + 2][ar] = a0.z; As[ac + 3][ar] = a0.w;
        As[ac + 4][ar] = a1.x; As[ac + 5][ar] = a1.y;
        As[ac + 6][ar] = a1.z; As[ac + 7][ar] = a1.w;
        *(float4*)&Ws[wr][wc] = wv;
        __syncthreads();
#pragma unroll
        for (int kk = 0; kk < BK; ++kk) {
            float4 x0 = *(const float4*)&As[kk][ty * 8];
            float4 x1 = *(const float4*)&As[kk][ty * 8 + 4];
            float4 bb = *(const float4*)&Ws[kk][tx * 4];
            acc[0][0] = fmaf(x0.x, bb.x, acc[0][0]); acc[0][1] = fmaf(x0.x, bb.y, acc[0][1]);
            acc[0][2] = fmaf(x0.x, bb.z, acc[0][2]); acc[0][3] = fmaf(x0.x, bb.w, acc[0][3]);
            acc[1][0] = fmaf(x0.y, bb.x, acc[1][0]); acc[1][1] = fmaf(x0.y, bb.y, acc[1][1]);
            acc[1][2] = fmaf(x0.y, bb.z, acc[1][2]); acc[1][3] = fmaf(x0.y, bb.w, acc[1][3]);
            acc[2][0] = fmaf(x0.z, bb.x, acc[2][0]); acc[2][1] = fmaf(x0.z, bb.y, acc[2][1]);
            acc[2][2] = fmaf(x0.z, bb.z, acc[2][2]); acc[2][3] = fmaf(x0.z, bb.w, acc[2][3]);
            acc[3][0] = fmaf(x0.w, bb.x, acc[3][0]); acc[3][1] = fmaf(x0.w, bb.y, acc[3][1]);
            acc[3][2] = fmaf(x0.w, bb.z, acc[3][2]); acc[3][3] = fmaf(x0.w, bb.w, acc[3][3]);
            acc[4][0] = fmaf(x1.x, bb.x, acc[4][0]); acc[4][1] = fmaf(x1.x, bb.y, acc[4][1]);
            acc[4][2] = fmaf(x1.x, bb.z, acc[4][2]); acc[4][3] = fmaf(x1.x, bb.w, acc[4][3]);
            acc[5][0] = fmaf(x1.y, bb.x, acc[5][0]); acc[5][1] = fmaf(x1.y, bb.y, acc[5][1]);
            acc[5][2] = fmaf(x1.y, bb.z, acc[5][2]); acc[5][3] = fmaf(x1.y, bb.w, acc[5][3]);
            acc[6][0] = fmaf(x1.z, bb.x, acc[6][0]); acc[6][1] = fmaf(x1.z, bb.y, acc[6][1]);
            acc[6][2] = fmaf(x1.z, bb.z, acc[6][2]); acc[6][3] = fmaf(x1.z, bb.w, acc[6][3]);
            acc[7][0] = fmaf(x1.w, bb.x, acc[7][0]); acc[7][1] = fmaf(x1.w, bb.y, acc[7][1]);
            acc[7][2] = fmaf(x1.w, bb.z, acc[7][2]); acc[7][3] = fmaf(x1.w, bb.w, acc[7][3]);
        }
    }
#pragma unroll
    for (int i = 0; i < 8; ++i) {
        int r = m0 + ty * 8 + i;
        if (r >= M) break;
        int c0 = n0 + tx * 4;
        float4 o;
        float* po = &o.x;
#pragma unroll
        for (int j = 0; j < 4; ++j) {
            float v = acc[i][j];
            if (bias) v += bias[(size_t)(r / 50) * N + c0 + j];
            if (act) v = gelu_f(v);
            po[j] = v;
        }
        *(float4*)(C + (size_t)r * N + c0) = o;
    }
}

// ---------------- attention: one block per (batch, head) ----------------
__global__ __launch_bounds__(256) void attn_kernel(const float* __restrict__ q,
                                                   const float* __restrict__ k,
                                                   const float* __restrict__ v,
                                                   float* __restrict__ ao) {
    __shared__ float sQ[NTOK * 132];  // q, later v (row stride 132 to break bank conflicts)
    __shared__ float sK[NTOK * 132];
    __shared__ float sS[NTOK * 51];
    int blk = blockIdx.x;
    int b = blk >> 1, h = blk & 1;
    const size_t base = (size_t)b * NTOK * C_DIM + h * HD;
    int tid = threadIdx.x;
    for (int idx = tid; idx < 1600; idx += 256) {
        int r = idx >> 5, c = (idx & 31) * 4;
        *(float4*)&sQ[r * 132 + c] = *(const float4*)(q + base + (size_t)r * C_DIM + c);
        *(float4*)&sK[r * 132 + c] = *(const float4*)(k + base + (size_t)r * C_DIM + c);
    }
    __syncthreads();
    for (int e = tid; e < NTOK * NTOK; e += 256) {
        int i = e / NTOK, j = e - i * NTOK;
        const float* qi = &sQ[i * 132];
        const float* kj = &sK[j * 132];
        float4 acc = {0.f, 0.f, 0.f, 0.f};
#pragma unroll
        for (int t = 0; t < 32; ++t) {
            float4 a = *(const float4*)&qi[t * 4];
            float4 bb = *(const float4*)&kj[t * 4];
            acc.x = fmaf(a.x, bb.x, acc.x); acc.y = fmaf(a.y, bb.y, acc.y);
            acc.z = fmaf(a.z, bb.z, acc.z); acc.w = fmaf(a.w, bb.w, acc.w);
        }
        sS[i * 51 + j] = (acc.x + acc.y + acc.z + acc.w) * 0.08838834764831845f; // 1/sqrt(128)
    }
    __syncthreads();
    // overwrite sQ with v; softmax rows in parallel
    for (int idx = tid; idx < 1600; idx += 256) {
        int r = idx >> 5, c = (idx & 31) * 4;
        *(float4*)&sQ[r * 132 + c] = *(const float4*)(v + base + (size_t)r * C_DIM + c);
    }
    if (tid < NTOK) {
        float* row = &sS[tid * 51];
        float m = row[0];
        for (int j = 1; j < NTOK; ++j) m = fmaxf(m, row[j]);
        float sum = 0.f;
        for (int j = 0; j < NTOK; ++j) { float e2 = expf(row[j] - m); row[j] = e2; sum += e2; }
        float inv = 1.0f / sum;
        for (int j = 0; j < NTOK; ++j) row[j] *= inv;
    }
    __syncthreads();
    for (int e = tid; e < NTOK * HD; e += 256) {
        int i = e >> 7, d = e & 127;
        const float* srow = &sS[i * 51];
        float acc = 0.f;
#pragma unroll
        for (int j = 0; j < NTOK; ++j) acc = fmaf(srow[j], sQ[j * 132 + d], acc);
        ao[base + (size_t)i * C_DIM + d] = acc;
    }
}

// ---------------- mean over the 50 tokens ----------------
__global__ __launch_bounds__(256) void mean50(const float* __restrict__ h2,
                                              float* __restrict__ g) {
    int b = blockIdx.x, c = threadIdx.x;
    float s = 0.f;
    for (int n = 0; n < NTOK; ++n) s += h2[((size_t)b * NTOK + n) * C_DIM + c];
    g[(size_t)b * C_DIM + c] = s / 50.0f;
}

// ---------------- pred = tanh(h3 @ w2): one wave per row ----------------
__global__ __launch_bounds__(256) void matvec_tanh(const float* __restrict__ h3,
                                                   const float* __restrict__ w2,
                                                   float* __restrict__ pred) {
    int row  = blockIdx.x * 4 + (threadIdx.x >> 6);
    int lane = threadIdx.x & 63;
    const float* rp = h3 + (size_t)row * C_DIM;
    float4 a = *(const float4*)(rp + lane * 4);
    float4 w = *(const float4*)(w2 + lane * 4);
    float s = a.x * w.x + a.y * w.y + a.z * w.z + a.w * w.w;
#pragma unroll
    for (int off = 32; off; off >>= 1) s += __shfl_xor(s, off);
    if (lane == 0) pred[row] = tanhf(s);
}

// ---------------- JAX threefry2x32 with key (0,1)  [jax.random.key(1)] ----------------
__device__ __forceinline__ uint32_t rotl32(uint32_t x, int r) {
    return (x << r) | (x >> (32 - r));
}
__device__ __forceinline__ void threefry01(uint32_t& x0, uint32_t& x1) {
    const uint32_t ks0 = 0u, ks1 = 1u, ks2 = 0x1BD11BDBu; // 0^1^0x1BD11BDA
    x0 += ks0; x1 += ks1;
#define TFR(r) { x0 += x1; x1 = rotl32(x1, r); x1 ^= x0; }
    TFR(13) TFR(15) TFR(26) TFR(6)  x0 += ks1; x1 += ks2 + 1u;
    TFR(17) TFR(29) TFR(16) TFR(24) x0 += ks2; x1 += ks0 + 2u;
    TFR(13) TFR(15) TFR(26) TFR(6)  x0 += ks0; x1 += ks1 + 3u;
    TFR(17) TFR(29) TFR(16) TFR(24) x0 += ks1; x1 += ks2 + 4u;
    TFR(13) TFR(15) TFR(26) TFR(6)  x0 += ks2; x1 += ks0 + 5u;
#undef TFR
}

// XLA/Giles single-precision erfinv
__device__ __forceinline__ float erfinv_xla(float x) {
    float w = -log1pf(-x * x);
    float p;
    if (w < 5.0f) {
        w -= 2.5f;
        p = 2.81022636e-08f;
        p = fmaf(p, w, 3.43273939e-07f);
        p = fmaf(p, w, -3.5233877e-06f);
        p = fmaf(p, w, -4.39150654e-06f);
        p = fmaf(p, w, 0.00021858087f);
        p = fmaf(p, w, -0.00125372503f);
        p = fmaf(p, w, -0.00417768164f);
        p = fmaf(p, w, 0.246640727f);
        p = fmaf(p, w, 1.50140941f);
    } else {
        w = sqrtf(w) - 3.0f;
        p = -0.000200214257f;
        p = fmaf(p, w, 0.000100950558f);
        p = fmaf(p, w, 0.00134934322f);
        p = fmaf(p, w, -0.00367342844f);
        p = fmaf(p, w, 0.00573950773f);
        p = fmaf(p, w, -0.0076224613f);
        p = fmaf(p, w, 0.00943887047f);
        p = fmaf(p, w, 1.00167406f);
        p = fmaf(p, w, 2.83297682f);
    }
    return p * x;
}

__device__ __forceinline__ float bits_to_normal(uint32_t bits) {
    // uniform in [-1+2^-24, 1): mantissa trick, scale=(1-lo) rounds to 2.0f, sqrt2*erfinv
    float f = __uint_as_float((bits >> 9) | 0x3f800000u) - 1.0f;
    float u = f * 2.0f + (-0.99999994039535522461f);
    u = fmaxf(-0.99999994039535522461f, u);
    return 1.4142135623730951f * erfinv_xla(u);
}

// Partitionable threefry (modern JAX default): element i <- threefry(key, (0, i)),
// 32-bit output = out0 ^ out1. One wave per (b, s) sample; lane = spatial position.
// Rank via monotone 64-bit key + v_readlane broadcast (no DS ops):
// key = mono(v) << 6 | (63 - lane); key_e > key_l  <=>  (v_e > v_l) || (v_e==v_l && e<l).
__global__ __launch_bounds__(256) void topk_kernel(const float* __restrict__ pred,
                                                   int* __restrict__ counts) {
    int wid  = (blockIdx.x * 256 + threadIdx.x) >> 6;  // 0..95999 = b*500 + s
    int lane = threadIdx.x & 63;
    int b = wid / NSAMP;
    int s = wid - b * NSAMP;
    uint32_t lo = (uint32_t)((b * NSAMP + s) * NSPA + lane);
    uint32_t x0 = 0u, x1 = lo;
    threefry01(x0, x1);
    float n = bits_to_normal(x0 ^ x1);
    float sc = (lane < NSPA) ? pred[b * NTOK + 2 + lane] : 0.f;
    float v  = (lane < NSPA) ? sc + n * 0.05f : -INFINITY;

    uint32_t vb   = __float_as_uint(v);
    uint32_t mono = (vb & 0x80000000u) ? ~vb : (vb | 0x80000000u);
    uint64_t key  = ((uint64_t)mono << 6) | (uint32_t)(63 - lane);
    uint32_t klo  = (uint32_t)key, khi = (uint32_t)(key >> 32);
    int rank = 0;
#pragma unroll
    for (int e = 0; e < NSPA; ++e) {
        uint32_t elo = (uint32_t)__builtin_amdgcn_readlane((int)klo, e);
        uint32_t ehi = (uint32_t)__builtin_amdgcn_readlane((int)khi, e);
        uint64_t ekey = ((uint64_t)ehi << 32) | elo;
        rank += (ekey > key) ? 1 : 0;
    }
    bool sel = (lane < NSPA) && (rank < TOPKK);
    unsigned long long mask = __ballot(sel);
    if (sel) {
        int kpos = __popcll(mask & ((1ull << lane) - 1ull));
        atomicAdd(&counts[((size_t)b * TOPKK + kpos) * NSPA + lane], 1);
    }
}

// ---------------- output assembly ----------------
__global__ __launch_bounds__(256) void select_out(const float* __restrict__ x,
                                                  const int* __restrict__ counts,
                                                  float* __restrict__ out) {
    int row = blockIdx.x;            // 0..2687 = b*14 + k
    int b = row / 14, k = row - b * 14;
    int d = threadIdx.x;             // 0..255; handles d and d+256
    if (k < 2) {
        out[(size_t)row * D_EMB + d]       = x[((size_t)(b * NTOK + k)) * D_EMB + d];
        out[(size_t)row * D_EMB + d + 256] = x[((size_t)(b * NTOK + k)) * D_EMB + d + 256];
    } else {
        int kk = k - 2;
        const int* cnt = counts + ((size_t)b * TOPKK + kk) * NSPA;
        __shared__ int sc[NSPA];
        if (d < NSPA) sc[d] = cnt[d];
        __syncthreads();
        float a0 = 0.f, a1 = 0.f;
        for (int l = 0; l < NSPA; ++l) {
            int c = sc[l];
            if (c) {
                float w = (float)c / 500.0f;
                const float* xr = x + ((size_t)(b * NTOK + 2 + l)) * D_EMB;
                a0 = fmaf(w, xr[d], a0);
                a1 = fmaf(w, xr[d + 256], a1);
            }
        }
        out[(size_t)row * D_EMB + d]       = a0;
        out[(size_t)row * D_EMB + d + 256] = a1;
    }
}

extern "C" void kernel_launch(void* const* d_in, const int* in_sizes, int n_in,
                              void* d_out, int out_size, void* d_ws, size_t ws_size,
                              hipStream_t stream) {
    const float* x    = (const float*)d_in[0];
    const float* ln_g = (const float*)d_in[1];
    const float* ln_b = (const float*)d_in[2];
    const float* w_in = (const float*)d_in[3];
    const float* wq   = (const float*)d_in[4];
    const float* wk   = (const float*)d_in[5];
    const float* wv   = (const float*)d_in[6];
    const float* wo   = (const float*)d_in[7];
    const float* w1   = (const float*)d_in[8];
    const float* w2   = (const float*)d_in[9];
    float* out = (float*)d_out;

    float* ws = (float*)d_ws;
    float* xn    = ws;                               // 9600*512
    float* h1    = xn + (size_t)ROWS * D_EMB;        // 9600*256
    float* q     = h1 + (size_t)ROWS * C_DIM;
    float* k     = q  + (size_t)ROWS * C_DIM;
    float* v     = k  + (size_t)ROWS * C_DIM;
    float* ao    = v  + (size_t)ROWS * C_DIM;
    float* gmean = ao + (size_t)ROWS * C_DIM;        // 192*256
    float* gw    = gmean + (size_t)B2 * C_DIM;       // 192*256
    float* pred  = gw + (size_t)B2 * C_DIM;          // 9600
    int*   counts = (int*)(pred + ROWS);             // 192*12*48 ints
    float* h2 = q;   // q dead after attention
    float* h3 = k;   // k dead after attention

    ln_kernel<<<ROWS / 4, 256, 0, stream>>>(x, ln_g, ln_b, xn);
    gemm_f32<<<dim3(ROWS / BM, C_DIM / BN), 256, 0, stream>>>(xn, w_in, h1, ROWS, C_DIM, D_EMB, nullptr, 1);
    gemm_f32<<<dim3(ROWS / BM, C_DIM / BN), 256, 0, stream>>>(h1, wq, q, ROWS, C_DIM, C_DIM, nullptr, 0);
    gemm_f32<<<dim3(ROWS / BM, C_DIM / BN), 256, 0, stream>>>(h1, wk, k, ROWS, C_DIM, C_DIM, nullptr, 0);
    gemm_f32<<<dim3(ROWS / BM, C_DIM / BN), 256, 0, stream>>>(h1, wv, v, ROWS, C_DIM, C_DIM, nullptr, 0);
    attn_kernel<<<B2 * 2, 256, 0, stream>>>(q, k, v, ao);
    gemm_f32<<<dim3(ROWS / BM, C_DIM / BN), 256, 0, stream>>>(ao, wo, h2, ROWS, C_DIM, C_DIM, nullptr, 0);
    mean50<<<B2, 256, 0, stream>>>(h2, gmean);
    gemm_f32<<<dim3((B2 + BM - 1) / BM, C_DIM / BN), 256, 0, stream>>>(gmean, w1 + (size_t)C_DIM * C_DIM, gw, B2, C_DIM, C_DIM, nullptr, 0);
    gemm_f32<<<dim3(ROWS / BM, C_DIM / BN), 256, 0, stream>>>(h2, w1, h3, ROWS, C_DIM, C_DIM, gw, 1);
    matvec_tanh<<<ROWS / 4, 256, 0, stream>>>(h3, w2, pred);
    hipMemsetAsync(counts, 0, (size_t)B2 * TOPKK * NSPA * sizeof(int), stream);
    topk_kernel<<<B2 * NSAMP / 4, 256, 0, stream>>>(pred, counts);
    select_out<<<B2 * 14, 256, 0, stream>>>(x, counts, out);
}

// Round 4
// 411.548 us; speedup vs baseline: 1.1362x; 1.1362x over previous
//
#include <hip/hip_runtime.h>
#include <stdint.h>

// ---------------- problem constants ----------------
#define B2      192          // 16 * MAX_FRAMES
#define NTOK    50           // tokens per frame-batch
#define ROWS    9600         // B2 * NTOK
#define D_EMB   512
#define C_DIM   256
#define HD      128          // head dim
#define NSAMP   500
#define TOPKK   12
#define NSPA    48           // 50 - SEL_DIM

__device__ __forceinline__ float gelu_f(float x) {
    return 0.5f * x * (1.0f + erff(x * 0.7071067811865476f));
}

// ---------------- LayerNorm: one wave per row of 512 ----------------
__global__ __launch_bounds__(256) void ln_kernel(const float* __restrict__ x,
                                                 const float* __restrict__ g,
                                                 const float* __restrict__ b,
                                                 float* __restrict__ xn) {
    int row  = blockIdx.x * 4 + (threadIdx.x >> 6);
    int lane = threadIdx.x & 63;
    const float* rp = x + (size_t)row * D_EMB;
    float4 v0 = *(const float4*)(rp + lane * 8);
    float4 v1 = *(const float4*)(rp + lane * 8 + 4);
    float s  = v0.x + v0.y + v0.z + v0.w + v1.x + v1.y + v1.z + v1.w;
    float s2 = v0.x*v0.x + v0.y*v0.y + v0.z*v0.z + v0.w*v0.w
             + v1.x*v1.x + v1.y*v1.y + v1.z*v1.z + v1.w*v1.w;
#pragma unroll
    for (int off = 32; off; off >>= 1) {
        s  += __shfl_xor(s,  off);
        s2 += __shfl_xor(s2, off);
    }
    float mu  = s / 512.0f;
    float var = s2 / 512.0f - mu * mu;
    float inv = 1.0f / sqrtf(var + 1e-5f);
    float* op = xn + (size_t)row * D_EMB;
    const float* gp = g + lane * 8;
    const float* bp = b + lane * 8;
    float4 o0, o1;
    o0.x = (v0.x - mu) * inv * gp[0] + bp[0];
    o0.y = (v0.y - mu) * inv * gp[1] + bp[1];
    o0.z = (v0.z - mu) * inv * gp[2] + bp[2];
    o0.w = (v0.w - mu) * inv * gp[3] + bp[3];
    o1.x = (v1.x - mu) * inv * gp[4] + bp[4];
    o1.y = (v1.y - mu) * inv * gp[5] + bp[5];
    o1.z = (v1.z - mu) * inv * gp[6] + bp[6];
    o1.w = (v1.w - mu) * inv * gp[7] + bp[7];
    *(float4*)(op + lane * 8)     = o0;
    *(float4*)(op + lane * 8 + 4) = o1;
}

// ---------------- fp32 tiled GEMM: C[M,N] = act(A[M,K] @ W[K,N] + bias) ----------------
// 64x64 tile, 256 threads, 4x4/thread, BK=32, register double-buffered staging.
// Requires M%64==0, N%64==0, K%32==0 (holds: M in {9600,192}, N=256, K in {256,512}).
// bias (if non-null) indexed [(row/50)*N + col]  (mean-pool concat trick).
#define BK 32
__global__ __launch_bounds__(256) void gemm_f32(const float* __restrict__ A,
                                                const float* __restrict__ W,
                                                float* __restrict__ C,
                                                int M, int N, int K,
                                                const float* __restrict__ bias,
                                                int act) {
    __shared__ float As[BK][68];  // [k][m], padded
    __shared__ float Ws[BK][64];  // [k][n]
    int m0 = blockIdx.x * 64, n0 = blockIdx.y * 64;
    int tid = threadIdx.x;
    int tm = tid >> 4, tn = tid & 15;
    int arow = tid >> 3;            // 0..31 (and +32 for second half)
    int acol = (tid & 7) * 4;       // k-offset 0..28
    int wrow = tid >> 4;            // 0..15 (and +16)
    int wcol = (tid & 15) * 4;      // col 0..60
    const float* Ab0 = A + (size_t)(m0 + arow) * K + acol;
    const float* Ab1 = Ab0 + (size_t)32 * K;
    const float* Wb0 = W + (size_t)wrow * N + n0 + wcol;
    const float* Wb1 = Wb0 + (size_t)16 * N;

    float4 a0 = *(const float4*)(Ab0);
    float4 a1 = *(const float4*)(Ab1);
    float4 w0 = *(const float4*)(Wb0);
    float4 w1 = *(const float4*)(Wb1);
    float acc[4][4] = {};
    int k0 = 0;
    for (;;) {
        As[acol + 0][arow]      = a0.x; As[acol + 1][arow]      = a0.y;
        As[acol + 2][arow]      = a0.z; As[acol + 3][arow]      = a0.w;
        As[acol + 0][arow + 32] = a1.x; As[acol + 1][arow + 32] = a1.y;
        As[acol + 2][arow + 32] = a1.z; As[acol + 3][arow + 32] = a1.w;
        *(float4*)&Ws[wrow][wcol]      = w0;
        *(float4*)&Ws[wrow + 16][wcol] = w1;
        __syncthreads();
        k0 += BK;
        bool more = k0 < K;
        if (more) {   // issue next-tile loads; they fly under the compute below
            a0 = *(const float4*)(Ab0 + k0);
            a1 = *(const float4*)(Ab1 + k0);
            w0 = *(const float4*)(Wb0 + (size_t)k0 * N);
            w1 = *(const float4*)(Wb1 + (size_t)k0 * N);
        }
#pragma unroll
        for (int kk = 0; kk < BK; ++kk) {
            float4 a = *(const float4*)&As[kk][tm * 4];
            float4 b = *(const float4*)&Ws[kk][tn * 4];
            acc[0][0] = fmaf(a.x, b.x, acc[0][0]); acc[0][1] = fmaf(a.x, b.y, acc[0][1]);
            acc[0][2] = fmaf(a.x, b.z, acc[0][2]); acc[0][3] = fmaf(a.x, b.w, acc[0][3]);
            acc[1][0] = fmaf(a.y, b.x, acc[1][0]); acc[1][1] = fmaf(a.y, b.y, acc[1][1]);
            acc[1][2] = fmaf(a.y, b.z, acc[1][2]); acc[1][3] = fmaf(a.y, b.w, acc[1][3]);
            acc[2][0] = fmaf(a.z, b.x, acc[2][0]); acc[2][1] = fmaf(a.z, b.y, acc[2][1]);
            acc[2][2] = fmaf(a.z, b.z, acc[2][2]); acc[2][3] = fmaf(a.z, b.w, acc[2][3]);
            acc[3][0] = fmaf(a.w, b.x, acc[3][0]); acc[3][1] = fmaf(a.w, b.y, acc[3][1]);
            acc[3][2] = fmaf(a.w, b.z, acc[3][2]); acc[3][3] = fmaf(a.w, b.w, acc[3][3]);
        }
        if (!more) break;
        __syncthreads();
    }
#pragma unroll
    for (int i = 0; i < 4; ++i) {
        int r = m0 + tm * 4 + i;
        int c0 = n0 + tn * 4;
        float4 o;
        float* po = &o.x;
#pragma unroll
        for (int j = 0; j < 4; ++j) {
            float v = acc[i][j];
            if (bias) v += bias[(size_t)(r / 50) * N + c0 + j];
            if (act) v = gelu_f(v);
            po[j] = v;
        }
        *(float4*)(C + (size_t)r * N + c0) = o;
    }
}

// ---------------- attention: one block per (batch, head) ----------------
__global__ __launch_bounds__(256) void attn_kernel(const float* __restrict__ q,
                                                   const float* __restrict__ k,
                                                   const float* __restrict__ v,
                                                   float* __restrict__ ao) {
    __shared__ float sQ[NTOK * 132];  // q, later v (row stride 132 to break bank conflicts)
    __shared__ float sK[NTOK * 132];
    __shared__ float sS[NTOK * 51];
    int blk = blockIdx.x;
    int b = blk >> 1, h = blk & 1;
    const size_t base = (size_t)b * NTOK * C_DIM + h * HD;
    int tid = threadIdx.x;
    for (int idx = tid; idx < 1600; idx += 256) {
        int r = idx >> 5, c = (idx & 31) * 4;
        *(float4*)&sQ[r * 132 + c] = *(const float4*)(q + base + (size_t)r * C_DIM + c);
        *(float4*)&sK[r * 132 + c] = *(const float4*)(k + base + (size_t)r * C_DIM + c);
    }
    __syncthreads();
    for (int e = tid; e < NTOK * NTOK; e += 256) {
        int i = e / NTOK, j = e - i * NTOK;
        const float* qi = &sQ[i * 132];
        const float* kj = &sK[j * 132];
        float4 acc = {0.f, 0.f, 0.f, 0.f};
#pragma unroll
        for (int t = 0; t < 32; ++t) {
            float4 a = *(const float4*)&qi[t * 4];
            float4 bb = *(const float4*)&kj[t * 4];
            acc.x = fmaf(a.x, bb.x, acc.x); acc.y = fmaf(a.y, bb.y, acc.y);
            acc.z = fmaf(a.z, bb.z, acc.z); acc.w = fmaf(a.w, bb.w, acc.w);
        }
        sS[i * 51 + j] = (acc.x + acc.y + acc.z + acc.w) * 0.08838834764831845f; // 1/sqrt(128)
    }
    __syncthreads();
    // overwrite sQ with v; softmax rows in parallel
    for (int idx = tid; idx < 1600; idx += 256) {
        int r = idx >> 5, c = (idx & 31) * 4;
        *(float4*)&sQ[r * 132 + c] = *(const float4*)(v + base + (size_t)r * C_DIM + c);
    }
    if (tid < NTOK) {
        float* row = &sS[tid * 51];
        float m = row[0];
        for (int j = 1; j < NTOK; ++j) m = fmaxf(m, row[j]);
        float sum = 0.f;
        for (int j = 0; j < NTOK; ++j) { float e2 = expf(row[j] - m); row[j] = e2; sum += e2; }
        float inv = 1.0f / sum;
        for (int j = 0; j < NTOK; ++j) row[j] *= inv;
    }
    __syncthreads();
    for (int e = tid; e < NTOK * HD; e += 256) {
        int i = e >> 7, d = e & 127;
        const float* srow = &sS[i * 51];
        float acc = 0.f;
#pragma unroll
        for (int j = 0; j < NTOK; ++j) acc = fmaf(srow[j], sQ[j * 132 + d], acc);
        ao[base + (size_t)i * C_DIM + d] = acc;
    }
}

// ---------------- mean over the 50 tokens ----------------
__global__ __launch_bounds__(256) void mean50(const float* __restrict__ h2,
                                              float* __restrict__ g) {
    int b = blockIdx.x, c = threadIdx.x;
    float s = 0.f;
    for (int n = 0; n < NTOK; ++n) s += h2[((size_t)b * NTOK + n) * C_DIM + c];
    g[(size_t)b * C_DIM + c] = s / 50.0f;
}

// ---------------- pred = tanh(h3 @ w2): one wave per row ----------------
__global__ __launch_bounds__(256) void matvec_tanh(const float* __restrict__ h3,
                                                   const float* __restrict__ w2,
                                                   float* __restrict__ pred) {
    int row  = blockIdx.x * 4 + (threadIdx.x >> 6);
    int lane = threadIdx.x & 63;
    const float* rp = h3 + (size_t)row * C_DIM;
    float4 a = *(const float4*)(rp + lane * 4);
    float4 w = *(const float4*)(w2 + lane * 4);
    float s = a.x * w.x + a.y * w.y + a.z * w.z + a.w * w.w;
#pragma unroll
    for (int off = 32; off; off >>= 1) s += __shfl_xor(s, off);
    if (lane == 0) pred[row] = tanhf(s);
}

// ---------------- JAX threefry2x32 with key (0,1)  [jax.random.key(1)] ----------------
__device__ __forceinline__ uint32_t rotl32(uint32_t x, int r) {
    return (x << r) | (x >> (32 - r));
}
__device__ __forceinline__ void threefry01(uint32_t& x0, uint32_t& x1) {
    const uint32_t ks0 = 0u, ks1 = 1u, ks2 = 0x1BD11BDBu; // 0^1^0x1BD11BDA
    x0 += ks0; x1 += ks1;
#define TFR(r) { x0 += x1; x1 = rotl32(x1, r); x1 ^= x0; }
    TFR(13) TFR(15) TFR(26) TFR(6)  x0 += ks1; x1 += ks2 + 1u;
    TFR(17) TFR(29) TFR(16) TFR(24) x0 += ks2; x1 += ks0 + 2u;
    TFR(13) TFR(15) TFR(26) TFR(6)  x0 += ks0; x1 += ks1 + 3u;
    TFR(17) TFR(29) TFR(16) TFR(24) x0 += ks1; x1 += ks2 + 4u;
    TFR(13) TFR(15) TFR(26) TFR(6)  x0 += ks2; x1 += ks0 + 5u;
#undef TFR
}

// XLA/Giles single-precision erfinv
__device__ __forceinline__ float erfinv_xla(float x) {
    float w = -log1pf(-x * x);
    float p;
    if (w < 5.0f) {
        w -= 2.5f;
        p = 2.81022636e-08f;
        p = fmaf(p, w, 3.43273939e-07f);
        p = fmaf(p, w, -3.5233877e-06f);
        p = fmaf(p, w, -4.39150654e-06f);
        p = fmaf(p, w, 0.00021858087f);
        p = fmaf(p, w, -0.00125372503f);
        p = fmaf(p, w, -0.00417768164f);
        p = fmaf(p, w, 0.246640727f);
        p = fmaf(p, w, 1.50140941f);
    } else {
        w = sqrtf(w) - 3.0f;
        p = -0.000200214257f;
        p = fmaf(p, w, 0.000100950558f);
        p = fmaf(p, w, 0.00134934322f);
        p = fmaf(p, w, -0.00367342844f);
        p = fmaf(p, w, 0.00573950773f);
        p = fmaf(p, w, -0.0076224613f);
        p = fmaf(p, w, 0.00943887047f);
        p = fmaf(p, w, 1.00167406f);
        p = fmaf(p, w, 2.83297682f);
    }
    return p * x;
}

__device__ __forceinline__ float bits_to_normal(uint32_t bits) {
    // uniform in [-1+2^-24, 1): mantissa trick, scale=(1-lo) rounds to 2.0f, sqrt2*erfinv
    float f = __uint_as_float((bits >> 9) | 0x3f800000u) - 1.0f;
    float u = f * 2.0f + (-0.99999994039535522461f);
    u = fmaxf(-0.99999994039535522461f, u);
    return 1.4142135623730951f * erfinv_xla(u);
}

// Partitionable threefry (modern JAX default): element i <- threefry(key, (0, i)),
// 32-bit output = out0 ^ out1. One wave per (b, s) sample; lane = spatial position.
// Selection: wave-uniform binary search for the 12th-largest monotone key (mostly
// SALU co-issue), exact stable tie-break (value desc, index asc) via ballot masks.
__global__ __launch_bounds__(256) void topk_kernel(const float* __restrict__ pred,
                                                   int* __restrict__ counts) {
    int wid  = (blockIdx.x * 256 + threadIdx.x) >> 6;  // 0..95999 = b*500 + s
    int lane = threadIdx.x & 63;
    int b = wid / NSAMP;
    int s = wid - b * NSAMP;
    uint32_t lo = (uint32_t)((b * NSAMP + s) * NSPA + lane);
    uint32_t x0 = 0u, x1 = lo;
    threefry01(x0, x1);
    float n = bits_to_normal(x0 ^ x1);
    float sc = (lane < NSPA) ? pred[b * NTOK + 2 + lane] : 0.f;
    float v  = (lane < NSPA) ? sc + n * 0.05f : -INFINITY;

    uint32_t vb   = __float_as_uint(v);
    uint32_t mono = (vb & 0x80000000u) ? ~vb : (vb | 0x80000000u);
    // idle lanes (v=-INF) -> mono=0x007FFFFF, strictly below every finite key.
    uint32_t t = 0;
#pragma unroll
    for (int bit = 31; bit >= 0; --bit) {
        uint32_t c = t | (1u << bit);
        unsigned long long m = __ballot(mono >= c);
        if (__popcll(m) >= TOPKK) t = c;   // wave-uniform: s_cselect
    }
    // t == 12th-largest key. Select mono>t, fill remainder among mono==t by lane order.
    unsigned long long mgt = __ballot(mono > t);
    unsigned long long meq = __ballot(mono == t);
    int r = TOPKK - __popcll(mgt);
    unsigned long long below = (1ull << lane) - 1ull;
    bool sel = (mono > t) || ((mono == t) && (__popcll(meq & below) < r));
    sel = sel && (lane < NSPA);
    unsigned long long mask = __ballot(sel);
    if (sel) {
        int kpos = __popcll(mask & below);
        atomicAdd(&counts[((size_t)b * TOPKK + kpos) * NSPA + lane], 1);
    }
}

// ---------------- output assembly ----------------
__global__ __launch_bounds__(256) void select_out(const float* __restrict__ x,
                                                  const int* __restrict__ counts,
                                                  float* __restrict__ out) {
    int row = blockIdx.x;            // 0..2687 = b*14 + k
    int b = row / 14, k = row - b * 14;
    int d = threadIdx.x;             // 0..255; handles d and d+256
    if (k < 2) {
        out[(size_t)row * D_EMB + d]       = x[((size_t)(b * NTOK + k)) * D_EMB + d];
        out[(size_t)row * D_EMB + d + 256] = x[((size_t)(b * NTOK + k)) * D_EMB + d + 256];
    } else {
        int kk = k - 2;
        const int* cnt = counts + ((size_t)b * TOPKK + kk) * NSPA;
        __shared__ int sc[NSPA];
        if (d < NSPA) sc[d] = cnt[d];
        __syncthreads();
        float a0 = 0.f, a1 = 0.f;
        for (int l = 0; l < NSPA; ++l) {
            int c = sc[l];
            if (c) {
                float w = (float)c / 500.0f;
                const float* xr = x + ((size_t)(b * NTOK + 2 + l)) * D_EMB;
                a0 = fmaf(w, xr[d], a0);
                a1 = fmaf(w, xr[d + 256], a1);
            }
        }
        out[(size_t)row * D_EMB + d]       = a0;
        out[(size_t)row * D_EMB + d + 256] = a1;
    }
}

extern "C" void kernel_launch(void* const* d_in, const int* in_sizes, int n_in,
                              void* d_out, int out_size, void* d_ws, size_t ws_size,
                              hipStream_t stream) {
    const float* x    = (const float*)d_in[0];
    const float* ln_g = (const float*)d_in[1];
    const float* ln_b = (const float*)d_in[2];
    const float* w_in = (const float*)d_in[3];
    const float* wq   = (const float*)d_in[4];
    const float* wk   = (const float*)d_in[5];
    const float* wv   = (const float*)d_in[6];
    const float* wo   = (const float*)d_in[7];
    const float* w1   = (const float*)d_in[8];
    const float* w2   = (const float*)d_in[9];
    float* out = (float*)d_out;

    float* ws = (float*)d_ws;
    float* xn    = ws;                               // 9600*512
    float* h1    = xn + (size_t)ROWS * D_EMB;        // 9600*256
    float* q     = h1 + (size_t)ROWS * C_DIM;
    float* k     = q  + (size_t)ROWS * C_DIM;
    float* v     = k  + (size_t)ROWS * C_DIM;
    float* ao    = v  + (size_t)ROWS * C_DIM;
    float* gmean = ao + (size_t)ROWS * C_DIM;        // 192*256
    float* gw    = gmean + (size_t)B2 * C_DIM;       // 192*256
    float* pred  = gw + (size_t)B2 * C_DIM;          // 9600
    int*   counts = (int*)(pred + ROWS);             // 192*12*48 ints
    float* h2 = q;   // q dead after attention
    float* h3 = k;   // k dead after attention

    ln_kernel<<<ROWS / 4, 256, 0, stream>>>(x, ln_g, ln_b, xn);
    gemm_f32<<<dim3(ROWS / 64, C_DIM / 64), 256, 0, stream>>>(xn, w_in, h1, ROWS, C_DIM, D_EMB, nullptr, 1);
    gemm_f32<<<dim3(ROWS / 64, C_DIM / 64), 256, 0, stream>>>(h1, wq, q, ROWS, C_DIM, C_DIM, nullptr, 0);
    gemm_f32<<<dim3(ROWS / 64, C_DIM / 64), 256, 0, stream>>>(h1, wk, k, ROWS, C_DIM, C_DIM, nullptr, 0);
    gemm_f32<<<dim3(ROWS / 64, C_DIM / 64), 256, 0, stream>>>(h1, wv, v, ROWS, C_DIM, C_DIM, nullptr, 0);
    attn_kernel<<<B2 * 2, 256, 0, stream>>>(q, k, v, ao);
    gemm_f32<<<dim3(ROWS / 64, C_DIM / 64), 256, 0, stream>>>(ao, wo, h2, ROWS, C_DIM, C_DIM, nullptr, 0);
    mean50<<<B2, 256, 0, stream>>>(h2, gmean);
    gemm_f32<<<dim3(B2 / 64, C_DIM / 64), 256, 0, stream>>>(gmean, w1 + (size_t)C_DIM * C_DIM, gw, B2, C_DIM, C_DIM, nullptr, 0);
    gemm_f32<<<dim3(ROWS / 64, C_DIM / 64), 256, 0, stream>>>(h2, w1, h3, ROWS, C_DIM, C_DIM, gw, 1);
    matvec_tanh<<<ROWS / 4, 256, 0, stream>>>(h3, w2, pred);
    hipMemsetAsync(counts, 0, (size_t)B2 * TOPKK * NSPA * sizeof(int), stream);
    topk_kernel<<<B2 * NSAMP / 4, 256, 0, stream>>>(pred, counts);
    select_out<<<B2 * 14, 256, 0, stream>>>(x, counts, out);
}

// Round 5
// 344.463 us; speedup vs baseline: 1.3575x; 1.1948x over previous
//
#include <hip/hip_runtime.h>
#include <stdint.h>

// ---------------- problem constants ----------------
#define B2      192          // 16 * MAX_FRAMES
#define NTOK    50           // tokens per frame-batch
#define ROWS    9600         // B2 * NTOK
#define D_EMB   512
#define C_DIM   256
#define HD      128          // head dim
#define NSAMP   500
#define TOPKK   12
#define NSPA    48           // 50 - SEL_DIM

typedef short short8 __attribute__((ext_vector_type(8)));
typedef float f32x4  __attribute__((ext_vector_type(4)));

__device__ __forceinline__ float gelu_f(float x) {
    return 0.5f * x * (1.0f + erff(x * 0.7071067811865476f));
}
__device__ __forceinline__ uint16_t f2bf(float x) {   // RNE fp32->bf16
    uint32_t u = __float_as_uint(x);
    return (uint16_t)((u + 0x7fffu + ((u >> 16) & 1u)) >> 16);
}
__device__ __forceinline__ float bf2f(uint16_t b) {
    return __uint_as_float(((uint32_t)b) << 16);
}
// swizzled A-operand halfword index for consumer-K (frag-contiguous MFMA layout)
__device__ __forceinline__ size_t swzA(int m, int k, int K) {
    return ((size_t)(m >> 4) * (K >> 5) + (k >> 5)) * 512
         + (size_t)((((k >> 3) & 3) * 16 + (m & 15)) * 8 + (k & 7));
}

// ---------------- LayerNorm: one wave per row; writes swizzled hi/lo bf16 ----------------
__global__ __launch_bounds__(256) void ln_kernel(const float* __restrict__ x,
                                                 const float* __restrict__ g,
                                                 const float* __restrict__ b,
                                                 short* __restrict__ xh,
                                                 short* __restrict__ xl) {
    int row  = blockIdx.x * 4 + (threadIdx.x >> 6);
    int lane = threadIdx.x & 63;
    const float* rp = x + (size_t)row * D_EMB;
    float4 v0 = *(const float4*)(rp + lane * 8);
    float4 v1 = *(const float4*)(rp + lane * 8 + 4);
    float s  = v0.x + v0.y + v0.z + v0.w + v1.x + v1.y + v1.z + v1.w;
    float s2 = v0.x*v0.x + v0.y*v0.y + v0.z*v0.z + v0.w*v0.w
             + v1.x*v1.x + v1.y*v1.y + v1.z*v1.z + v1.w*v1.w;
#pragma unroll
    for (int off = 32; off; off >>= 1) {
        s  += __shfl_xor(s,  off);
        s2 += __shfl_xor(s2, off);
    }
    float mu  = s / 512.0f;
    float var = s2 / 512.0f - mu * mu;
    float inv = 1.0f / sqrtf(var + 1e-5f);
    const float* gp = g + lane * 8;
    const float* bp = b + lane * 8;
    float o[8];
    o[0]=(v0.x-mu)*inv*gp[0]+bp[0]; o[1]=(v0.y-mu)*inv*gp[1]+bp[1];
    o[2]=(v0.z-mu)*inv*gp[2]+bp[2]; o[3]=(v0.w-mu)*inv*gp[3]+bp[3];
    o[4]=(v1.x-mu)*inv*gp[4]+bp[4]; o[5]=(v1.y-mu)*inv*gp[5]+bp[5];
    o[6]=(v1.z-mu)*inv*gp[6]+bp[6]; o[7]=(v1.w-mu)*inv*gp[7]+bp[7];
    short8 h8, l8;
#pragma unroll
    for (int j = 0; j < 8; ++j) {
        uint16_t h = f2bf(o[j]);
        h8[j] = (short)h;
        l8[j] = (short)f2bf(o[j] - bf2f(h));
    }
    // k = lane*8..+7, K=512 -> block (row>>4, lane>>2), inner (lane&3)*16 + row&15
    size_t blk = (size_t)(row >> 4) * 16 + (lane >> 2);
    int inner  = (lane & 3) * 16 + (row & 15);
    ((short8*)xh)[blk * 64 + inner] = h8;
    ((short8*)xl)[blk * 64 + inner] = l8;
}

// ---------------- weight fp32 -> swizzled hi/lo bf16 (B-operand layout) ----------------
// thread t: n = t&255, k8 = t>>8 (8 consecutive k for one fragment slot)
__global__ __launch_bounds__(256) void swz_w(const float* __restrict__ W,
                                             short* __restrict__ hi,
                                             short* __restrict__ lo, int K) {
    int t = blockIdx.x * 256 + threadIdx.x;
    int n = t & 255, k8 = t >> 8;
    short8 h8, l8;
#pragma unroll
    for (int j = 0; j < 8; ++j) {
        float wv = W[(size_t)(k8 * 8 + j) * 256 + n];
        uint16_t h = f2bf(wv);
        h8[j] = (short)h;
        l8[j] = (short)f2bf(wv - bf2f(h));
    }
    size_t blk = (size_t)(n >> 4) * (K >> 5) + (k8 >> 2);
    int inner  = (k8 & 3) * 16 + (n & 15);
    ((short8*)hi)[blk * 64 + inner] = h8;
    ((short8*)lo)[blk * 64 + inner] = l8;
}

// ---------------- split-bf16 MFMA GEMM ----------------
// C[M,N] = act(A@W + bias). A,B pre-swizzled frag-major hi/lo. Block=4 waves;
// wave w does m-strip (blockIdx.x*4+w) x 4 n-strips (blockIdx.y*4..+3).
// Writes fp32 row-major C (if Cf) and/or swizzled hi/lo bf16 for next GEMM (if Chi).
__global__ __launch_bounds__(256) void gemm_mfma(const short8* __restrict__ Ah,
                                                 const short8* __restrict__ Al,
                                                 const short8* __restrict__ Bh,
                                                 const short8* __restrict__ Bl,
                                                 float* __restrict__ Cf,
                                                 short* __restrict__ Chi,
                                                 short* __restrict__ Clo,
                                                 int K, int N,
                                                 const float* __restrict__ bias,
                                                 int act) {
    int lane = threadIdx.x & 63;
    int wv   = threadIdx.x >> 6;
    int ms   = blockIdx.x * 4 + wv;
    int ns0  = blockIdx.y * 4;
    int kb   = K >> 5;
    const short8* pAh = Ah + (size_t)ms * kb * 64 + lane;
    const short8* pAl = Al + (size_t)ms * kb * 64 + lane;
    const short8* pBh[4];
    const short8* pBl[4];
#pragma unroll
    for (int t = 0; t < 4; ++t) {
        pBh[t] = Bh + (size_t)(ns0 + t) * kb * 64 + lane;
        pBl[t] = Bl + (size_t)(ns0 + t) * kb * 64 + lane;
    }
    f32x4 acc[4] = {{0.f,0.f,0.f,0.f},{0.f,0.f,0.f,0.f},{0.f,0.f,0.f,0.f},{0.f,0.f,0.f,0.f}};
    short8 ah = pAh[0], al = pAl[0];
    short8 bh[4], bl[4];
#pragma unroll
    for (int t = 0; t < 4; ++t) { bh[t] = pBh[t][0]; bl[t] = pBl[t][0]; }
    for (int ks = 0;;) {
        short8 nah, nal, nbh[4], nbl[4];
        bool more = (ks + 1 < kb);
        int nxt = (ks + 1) * 64;
        if (more) {
            nah = pAh[nxt]; nal = pAl[nxt];
#pragma unroll
            for (int t = 0; t < 4; ++t) { nbh[t] = pBh[t][nxt]; nbl[t] = pBl[t][nxt]; }
        }
#pragma unroll
        for (int t = 0; t < 4; ++t) {
            acc[t] = __builtin_amdgcn_mfma_f32_16x16x32_bf16(ah, bh[t], acc[t], 0, 0, 0);
            acc[t] = __builtin_amdgcn_mfma_f32_16x16x32_bf16(ah, bl[t], acc[t], 0, 0, 0);
            acc[t] = __builtin_amdgcn_mfma_f32_16x16x32_bf16(al, bh[t], acc[t], 0, 0, 0);
        }
        if (!more) break;
        ah = nah; al = nal;
#pragma unroll
        for (int t = 0; t < 4; ++t) { bh[t] = nbh[t]; bl[t] = nbl[t]; }
        ++ks;
    }
    int row0 = ms * 16 + (lane >> 4) * 4;
    int cin  = lane & 15;
#pragma unroll
    for (int t = 0; t < 4; ++t) {
        int col = (ns0 + t) * 16 + cin;
#pragma unroll
        for (int r = 0; r < 4; ++r) {
            int row = row0 + r;
            float v2 = acc[t][r];
            if (bias) v2 += bias[(size_t)(row / 50) * N + col];
            if (act)  v2 = gelu_f(v2);
            if (Cf) Cf[(size_t)row * N + col] = v2;
            if (Chi) {
                uint16_t h = f2bf(v2);
                size_t ad = swzA(row, col, 256);
                Chi[ad] = (short)h;
                Clo[ad] = (short)f2bf(v2 - bf2f(h));
            }
        }
    }
}

// ---------------- attention: one block per (batch, head); writes swizzled ao ----------------
__global__ __launch_bounds__(256) void attn_kernel(const float* __restrict__ q,
                                                   const float* __restrict__ k,
                                                   const float* __restrict__ v,
                                                   short* __restrict__ aoh,
                                                   short* __restrict__ aol) {
    __shared__ float sQ[NTOK * 132];
    __shared__ float sK[NTOK * 132];
    __shared__ float sS[NTOK * 51];
    int blk = blockIdx.x;
    int b = blk >> 1, h = blk & 1;
    const size_t base = (size_t)b * NTOK * C_DIM + h * HD;
    int tid = threadIdx.x;
    for (int idx = tid; idx < 1600; idx += 256) {
        int r = idx >> 5, c = (idx & 31) * 4;
        *(float4*)&sQ[r * 132 + c] = *(const float4*)(q + base + (size_t)r * C_DIM + c);
        *(float4*)&sK[r * 132 + c] = *(const float4*)(k + base + (size_t)r * C_DIM + c);
    }
    __syncthreads();
    for (int e = tid; e < NTOK * NTOK; e += 256) {
        int i = e / NTOK, j = e - i * NTOK;
        const float* qi = &sQ[i * 132];
        const float* kj = &sK[j * 132];
        float4 acc = {0.f, 0.f, 0.f, 0.f};
#pragma unroll
        for (int t = 0; t < 32; ++t) {
            float4 a = *(const float4*)&qi[t * 4];
            float4 bb = *(const float4*)&kj[t * 4];
            acc.x = fmaf(a.x, bb.x, acc.x); acc.y = fmaf(a.y, bb.y, acc.y);
            acc.z = fmaf(a.z, bb.z, acc.z); acc.w = fmaf(a.w, bb.w, acc.w);
        }
        sS[i * 51 + j] = (acc.x + acc.y + acc.z + acc.w) * 0.08838834764831845f;
    }
    __syncthreads();
    for (int idx = tid; idx < 1600; idx += 256) {
        int r = idx >> 5, c = (idx & 31) * 4;
        *(float4*)&sQ[r * 132 + c] = *(const float4*)(v + base + (size_t)r * C_DIM + c);
    }
    if (tid < NTOK) {
        float* row = &sS[tid * 51];
        float m = row[0];
        for (int j = 1; j < NTOK; ++j) m = fmaxf(m, row[j]);
        float sum = 0.f;
        for (int j = 0; j < NTOK; ++j) { float e2 = expf(row[j] - m); row[j] = e2; sum += e2; }
        float inv = 1.0f / sum;
        for (int j = 0; j < NTOK; ++j) row[j] *= inv;
    }
    __syncthreads();
    for (int e = tid; e < NTOK * HD; e += 256) {
        int i = e >> 7, d = e & 127;
        const float* srow = &sS[i * 51];
        float acc = 0.f;
#pragma unroll
        for (int j = 0; j < NTOK; ++j) acc = fmaf(srow[j], sQ[j * 132 + d], acc);
        int row = b * NTOK + i, col = h * HD + d;
        uint16_t hh = f2bf(acc);
        size_t ad = swzA(row, col, 256);
        aoh[ad] = (short)hh;
        aol[ad] = (short)f2bf(acc - bf2f(hh));
    }
}

// ---------------- mean over 50 tokens -> swizzled hi/lo bf16 ----------------
__global__ __launch_bounds__(256) void mean50(const float* __restrict__ h2,
                                              short* __restrict__ gh,
                                              short* __restrict__ gl) {
    int b = blockIdx.x, c = threadIdx.x;
    float s = 0.f;
    for (int n = 0; n < NTOK; ++n) s += h2[((size_t)b * NTOK + n) * C_DIM + c];
    float g = s / 50.0f;
    uint16_t h = f2bf(g);
    size_t ad = swzA(b, c, 256);
    gh[ad] = (short)h;
    gl[ad] = (short)f2bf(g - bf2f(h));
}

// ---------------- pred = tanh(h3 @ w2): one wave per row ----------------
__global__ __launch_bounds__(256) void matvec_tanh(const float* __restrict__ h3,
                                                   const float* __restrict__ w2,
                                                   float* __restrict__ pred) {
    int row  = blockIdx.x * 4 + (threadIdx.x >> 6);
    int lane = threadIdx.x & 63;
    const float* rp = h3 + (size_t)row * C_DIM;
    float4 a = *(const float4*)(rp + lane * 4);
    float4 w = *(const float4*)(w2 + lane * 4);
    float s = a.x * w.x + a.y * w.y + a.z * w.z + a.w * w.w;
#pragma unroll
    for (int off = 32; off; off >>= 1) s += __shfl_xor(s, off);
    if (lane == 0) pred[row] = tanhf(s);
}

// ---------------- JAX threefry2x32 with key (0,1) ----------------
__device__ __forceinline__ uint32_t rotl32(uint32_t x, int r) {
    return (x << r) | (x >> (32 - r));
}
__device__ __forceinline__ void threefry01(uint32_t& x0, uint32_t& x1) {
    const uint32_t ks0 = 0u, ks1 = 1u, ks2 = 0x1BD11BDBu;
    x0 += ks0; x1 += ks1;
#define TFR(r) { x0 += x1; x1 = rotl32(x1, r); x1 ^= x0; }
    TFR(13) TFR(15) TFR(26) TFR(6)  x0 += ks1; x1 += ks2 + 1u;
    TFR(17) TFR(29) TFR(16) TFR(24) x0 += ks2; x1 += ks0 + 2u;
    TFR(13) TFR(15) TFR(26) TFR(6)  x0 += ks0; x1 += ks1 + 3u;
    TFR(17) TFR(29) TFR(16) TFR(24) x0 += ks1; x1 += ks2 + 4u;
    TFR(13) TFR(15) TFR(26) TFR(6)  x0 += ks2; x1 += ks0 + 5u;
#undef TFR
}

__device__ __forceinline__ float erfinv_xla(float x) {
    float w = -log1pf(-x * x);
    float p;
    if (w < 5.0f) {
        w -= 2.5f;
        p = 2.81022636e-08f;
        p = fmaf(p, w, 3.43273939e-07f);
        p = fmaf(p, w, -3.5233877e-06f);
        p = fmaf(p, w, -4.39150654e-06f);
        p = fmaf(p, w, 0.00021858087f);
        p = fmaf(p, w, -0.00125372503f);
        p = fmaf(p, w, -0.00417768164f);
        p = fmaf(p, w, 0.246640727f);
        p = fmaf(p, w, 1.50140941f);
    } else {
        w = sqrtf(w) - 3.0f;
        p = -0.000200214257f;
        p = fmaf(p, w, 0.000100950558f);
        p = fmaf(p, w, 0.00134934322f);
        p = fmaf(p, w, -0.00367342844f);
        p = fmaf(p, w, 0.00573950773f);
        p = fmaf(p, w, -0.0076224613f);
        p = fmaf(p, w, 0.00943887047f);
        p = fmaf(p, w, 1.00167406f);
        p = fmaf(p, w, 2.83297682f);
    }
    return p * x;
}

__device__ __forceinline__ float bits_to_normal(uint32_t bits) {
    float f = __uint_as_float((bits >> 9) | 0x3f800000u) - 1.0f;
    float u = f * 2.0f + (-0.99999994039535522461f);
    u = fmaxf(-0.99999994039535522461f, u);
    return 1.4142135623730951f * erfinv_xla(u);
}

// Partitionable threefry; wave-uniform binary search for 12th-largest key + exact ties.
__global__ __launch_bounds__(256) void topk_kernel(const float* __restrict__ pred,
                                                   int* __restrict__ counts) {
    int wid  = (blockIdx.x * 256 + threadIdx.x) >> 6;
    int lane = threadIdx.x & 63;
    int b = wid / NSAMP;
    int s = wid - b * NSAMP;
    uint32_t lo = (uint32_t)((b * NSAMP + s) * NSPA + lane);
    uint32_t x0 = 0u, x1 = lo;
    threefry01(x0, x1);
    float n = bits_to_normal(x0 ^ x1);
    float sc = (lane < NSPA) ? pred[b * NTOK + 2 + lane] : 0.f;
    float v  = (lane < NSPA) ? sc + n * 0.05f : -INFINITY;

    uint32_t vb   = __float_as_uint(v);
    uint32_t mono = (vb & 0x80000000u) ? ~vb : (vb | 0x80000000u);
    uint32_t t = 0;
#pragma unroll
    for (int bit = 31; bit >= 0; --bit) {
        uint32_t c = t | (1u << bit);
        unsigned long long m = __ballot(mono >= c);
        if (__popcll(m) >= TOPKK) t = c;
    }
    unsigned long long mgt = __ballot(mono > t);
    unsigned long long meq = __ballot(mono == t);
    int r = TOPKK - __popcll(mgt);
    unsigned long long below = (1ull << lane) - 1ull;
    bool sel = (mono > t) || ((mono == t) && (__popcll(meq & below) < r));
    sel = sel && (lane < NSPA);
    unsigned long long mask = __ballot(sel);
    if (sel) {
        int kpos = __popcll(mask & below);
        atomicAdd(&counts[((size_t)b * TOPKK + kpos) * NSPA + lane], 1);
    }
}

// ---------------- output assembly ----------------
__global__ __launch_bounds__(256) void select_out(const float* __restrict__ x,
                                                  const int* __restrict__ counts,
                                                  float* __restrict__ out) {
    int row = blockIdx.x;
    int b = row / 14, k = row - b * 14;
    int d = threadIdx.x;
    if (k < 2) {
        out[(size_t)row * D_EMB + d]       = x[((size_t)(b * NTOK + k)) * D_EMB + d];
        out[(size_t)row * D_EMB + d + 256] = x[((size_t)(b * NTOK + k)) * D_EMB + d + 256];
    } else {
        int kk = k - 2;
        const int* cnt = counts + ((size_t)b * TOPKK + kk) * NSPA;
        __shared__ int sc[NSPA];
        if (d < NSPA) sc[d] = cnt[d];
        __syncthreads();
        float a0 = 0.f, a1 = 0.f;
        for (int l = 0; l < NSPA; ++l) {
            int c = sc[l];
            if (c) {
                float w = (float)c / 500.0f;
                const float* xr = x + ((size_t)(b * NTOK + 2 + l)) * D_EMB;
                a0 = fmaf(w, xr[d], a0);
                a1 = fmaf(w, xr[d + 256], a1);
            }
        }
        out[(size_t)row * D_EMB + d]       = a0;
        out[(size_t)row * D_EMB + d + 256] = a1;
    }
}

extern "C" void kernel_launch(void* const* d_in, const int* in_sizes, int n_in,
                              void* d_out, int out_size, void* d_ws, size_t ws_size,
                              hipStream_t stream) {
    const float* x    = (const float*)d_in[0];
    const float* ln_g = (const float*)d_in[1];
    const float* ln_b = (const float*)d_in[2];
    const float* w_in = (const float*)d_in[3];
    const float* wq   = (const float*)d_in[4];
    const float* wk   = (const float*)d_in[5];
    const float* wv   = (const float*)d_in[6];
    const float* wo   = (const float*)d_in[7];
    const float* w1   = (const float*)d_in[8];
    const float* w2   = (const float*)d_in[9];
    float* out = (float*)d_out;

    char* W = (char*)d_ws;
    short* xn_hi  = (short*)(W + 0);            // 9,830,400 B
    short* xn_lo  = (short*)(W + 9830400);      // 9,830,400 B
    //   region reuse after xn is dead:
    short* ao_hi  = (short*)(W + 0);            // 4,915,200
    short* ao_lo  = (short*)(W + 4915200);      // 4,915,200
    short* h2_hi  = (short*)(W + 9830400);      // 4,915,200
    short* h2_lo  = (short*)(W + 14745600);     // 4,915,200
    short* h1_hi  = (short*)(W + 19660800);     // 4,915,200
    short* h1_lo  = (short*)(W + 24576000);     // 4,915,200
    float* h3     = (float*)(W + 19660800);     // 9,830,400 (aliases h1 after qkv)
    float* q      = (float*)(W + 29491200);     // 9,830,400
    float* h2f    = (float*)(W + 29491200);     // aliases q after attn
    float* k      = (float*)(W + 39321600);     // 9,830,400
    float* v      = (float*)(W + 49152000);     // 9,830,400
    short* win_hi = (short*)(W + 58982400);     // 262,144
    short* win_lo = (short*)(W + 59244544);
    short* wq_hi  = (short*)(W + 59506688);     // 131,072 each from here
    short* wq_lo  = (short*)(W + 59637760);
    short* wk_hi  = (short*)(W + 59768832);
    short* wk_lo  = (short*)(W + 59899904);
    short* wv_hi  = (short*)(W + 60030976);
    short* wv_lo  = (short*)(W + 60162048);
    short* wo_hi  = (short*)(W + 60293120);
    short* wo_lo  = (short*)(W + 60424192);
    short* w1a_hi = (short*)(W + 60555264);
    short* w1a_lo = (short*)(W + 60686336);
    short* w1b_hi = (short*)(W + 60817408);
    short* w1b_lo = (short*)(W + 60948480);
    short* gm_hi  = (short*)(W + 61079552);     // 98,304
    short* gm_lo  = (short*)(W + 61177856);     // 98,304
    float* gw     = (float*)(W + 61276160);     // 196,608
    float* pred   = (float*)(W + 61472768);     // 38,400
    int*   counts = (int*)  (W + 61511168);     // 442,368

    // 1. LN -> swizzled xn (K=512 layout)
    ln_kernel<<<ROWS / 4, 256, 0, stream>>>(x, ln_g, ln_b, xn_hi, xn_lo);
    // 2. weight swizzles
    swz_w<<<64, 256, 0, stream>>>(w_in, win_hi, win_lo, 512);
    swz_w<<<32, 256, 0, stream>>>(wq, wq_hi, wq_lo, 256);
    swz_w<<<32, 256, 0, stream>>>(wk, wk_hi, wk_lo, 256);
    swz_w<<<32, 256, 0, stream>>>(wv, wv_hi, wv_lo, 256);
    swz_w<<<32, 256, 0, stream>>>(wo, wo_hi, wo_lo, 256);
    swz_w<<<32, 256, 0, stream>>>(w1, w1a_hi, w1a_lo, 256);
    swz_w<<<32, 256, 0, stream>>>(w1 + 256 * 256, w1b_hi, w1b_lo, 256);
    // 3. h1 = gelu(xn @ w_in)  (swizzled out only)
    gemm_mfma<<<dim3(150, 4), 256, 0, stream>>>((const short8*)xn_hi, (const short8*)xn_lo,
        (const short8*)win_hi, (const short8*)win_lo, nullptr, h1_hi, h1_lo, 512, 256, nullptr, 1);
    // 4. q/k/v = h1 @ w{q,k,v}  (fp32 out)
    gemm_mfma<<<dim3(150, 4), 256, 0, stream>>>((const short8*)h1_hi, (const short8*)h1_lo,
        (const short8*)wq_hi, (const short8*)wq_lo, q, nullptr, nullptr, 256, 256, nullptr, 0);
    gemm_mfma<<<dim3(150, 4), 256, 0, stream>>>((const short8*)h1_hi, (const short8*)h1_lo,
        (const short8*)wk_hi, (const short8*)wk_lo, k, nullptr, nullptr, 256, 256, nullptr, 0);
    gemm_mfma<<<dim3(150, 4), 256, 0, stream>>>((const short8*)h1_hi, (const short8*)h1_lo,
        (const short8*)wv_hi, (const short8*)wv_lo, v, nullptr, nullptr, 256, 256, nullptr, 0);
    // 5. attention -> swizzled ao (xn region now dead)
    attn_kernel<<<B2 * 2, 256, 0, stream>>>(q, k, v, ao_hi, ao_lo);
    // 6. h2 = ao @ wo  (fp32 into old q + swizzled)
    gemm_mfma<<<dim3(150, 4), 256, 0, stream>>>((const short8*)ao_hi, (const short8*)ao_lo,
        (const short8*)wo_hi, (const short8*)wo_lo, h2f, h2_hi, h2_lo, 256, 256, nullptr, 0);
    // 7. gmean (swizzled)
    mean50<<<B2, 256, 0, stream>>>(h2f, gm_hi, gm_lo);
    // 8. gw = gmean @ w1[256:]  (fp32)
    gemm_mfma<<<dim3(3, 4), 256, 0, stream>>>((const short8*)gm_hi, (const short8*)gm_lo,
        (const short8*)w1b_hi, (const short8*)w1b_lo, gw, nullptr, nullptr, 256, 256, nullptr, 0);
    // 9. h3 = gelu(h2 @ w1[:256] + gw-bias)  (fp32, into old h1 region)
    gemm_mfma<<<dim3(150, 4), 256, 0, stream>>>((const short8*)h2_hi, (const short8*)h2_lo,
        (const short8*)w1a_hi, (const short8*)w1a_lo, h3, nullptr, nullptr, 256, 256, gw, 1);
    // 10. scores, topk, output
    matvec_tanh<<<ROWS / 4, 256, 0, stream>>>(h3, w2, pred);
    hipMemsetAsync(counts, 0, (size_t)B2 * TOPKK * NSPA * sizeof(int), stream);
    topk_kernel<<<B2 * NSAMP / 4, 256, 0, stream>>>(pred, counts);
    select_out<<<B2 * 14, 256, 0, stream>>>(x, counts, out);
}

// Round 6
// 313.635 us; speedup vs baseline: 1.4909x; 1.0983x over previous
//
#include <hip/hip_runtime.h>
#include <stdint.h>

// ---------------- problem constants ----------------
#define B2      192          // 16 * MAX_FRAMES
#define NTOK    50           // tokens per frame-batch
#define ROWS    9600         // B2 * NTOK
#define D_EMB   512
#define C_DIM   256
#define HD      128          // head dim
#define NSAMP   500
#define TOPKK   12
#define NSPA    48           // 50 - SEL_DIM

typedef short short8 __attribute__((ext_vector_type(8)));
typedef float f32x4  __attribute__((ext_vector_type(4)));

__device__ __forceinline__ float gelu_f(float x) {
    return 0.5f * x * (1.0f + erff(x * 0.7071067811865476f));
}
__device__ __forceinline__ uint16_t f2bf(float x) {   // RNE fp32->bf16
    uint32_t u = __float_as_uint(x);
    return (uint16_t)((u + 0x7fffu + ((u >> 16) & 1u)) >> 16);
}
__device__ __forceinline__ float bf2f(uint16_t b) {
    return __uint_as_float(((uint32_t)b) << 16);
}
// swizzled A-operand halfword index (frag-contiguous MFMA layout)
__device__ __forceinline__ size_t swzA(int m, int k, int K) {
    return ((size_t)(m >> 4) * (K >> 5) + (k >> 5)) * 512
         + (size_t)((((k >> 3) & 3) * 16 + (m & 15)) * 8 + (k & 7));
}

// ---------------- LayerNorm: one wave per row; writes swizzled hi/lo bf16 ----------------
__global__ __launch_bounds__(256) void ln_kernel(const float* __restrict__ x,
                                                 const float* __restrict__ g,
                                                 const float* __restrict__ b,
                                                 short* __restrict__ xh,
                                                 short* __restrict__ xl) {
    int row  = blockIdx.x * 4 + (threadIdx.x >> 6);
    int lane = threadIdx.x & 63;
    const float* rp = x + (size_t)row * D_EMB;
    float4 v0 = *(const float4*)(rp + lane * 8);
    float4 v1 = *(const float4*)(rp + lane * 8 + 4);
    float s  = v0.x + v0.y + v0.z + v0.w + v1.x + v1.y + v1.z + v1.w;
    float s2 = v0.x*v0.x + v0.y*v0.y + v0.z*v0.z + v0.w*v0.w
             + v1.x*v1.x + v1.y*v1.y + v1.z*v1.z + v1.w*v1.w;
#pragma unroll
    for (int off = 32; off; off >>= 1) {
        s  += __shfl_xor(s,  off);
        s2 += __shfl_xor(s2, off);
    }
    float mu  = s / 512.0f;
    float var = s2 / 512.0f - mu * mu;
    float inv = 1.0f / sqrtf(var + 1e-5f);
    const float* gp = g + lane * 8;
    const float* bp = b + lane * 8;
    float o[8];
    o[0]=(v0.x-mu)*inv*gp[0]+bp[0]; o[1]=(v0.y-mu)*inv*gp[1]+bp[1];
    o[2]=(v0.z-mu)*inv*gp[2]+bp[2]; o[3]=(v0.w-mu)*inv*gp[3]+bp[3];
    o[4]=(v1.x-mu)*inv*gp[4]+bp[4]; o[5]=(v1.y-mu)*inv*gp[5]+bp[5];
    o[6]=(v1.z-mu)*inv*gp[6]+bp[6]; o[7]=(v1.w-mu)*inv*gp[7]+bp[7];
    short8 h8, l8;
#pragma unroll
    for (int j = 0; j < 8; ++j) {
        uint16_t h = f2bf(o[j]);
        h8[j] = (short)h;
        l8[j] = (short)f2bf(o[j] - bf2f(h));
    }
    size_t blk = (size_t)(row >> 4) * 16 + (lane >> 2);
    int inner  = (lane & 3) * 16 + (row & 15);
    ((short8*)xh)[blk * 64 + inner] = h8;
    ((short8*)xl)[blk * 64 + inner] = l8;
}

// ---------------- all weights fp32 -> swizzled hi/lo bf16 (B-operand layout), one launch ----------------
__global__ __launch_bounds__(256) void swz_all(const float* __restrict__ w_in, const float* __restrict__ wq,
                                               const float* __restrict__ wk, const float* __restrict__ wv,
                                               const float* __restrict__ wo, const float* __restrict__ w1,
                                               short* win_hi, short* win_lo, short* wq_hi, short* wq_lo,
                                               short* wk_hi, short* wk_lo, short* wv_hi, short* wv_lo,
                                               short* wo_hi, short* wo_lo, short* w1a_hi, short* w1a_lo,
                                               short* w1b_hi, short* w1b_lo) {
    int blk = blockIdx.x;
    const float* W; short *hi, *lo; int K, base;
    if      (blk <  64) { W = w_in;            hi = win_hi; lo = win_lo; K = 512; base = 0;   }
    else if (blk <  96) { W = wq;              hi = wq_hi;  lo = wq_lo;  K = 256; base = 64;  }
    else if (blk < 128) { W = wk;              hi = wk_hi;  lo = wk_lo;  K = 256; base = 96;  }
    else if (blk < 160) { W = wv;              hi = wv_hi;  lo = wv_lo;  K = 256; base = 128; }
    else if (blk < 192) { W = wo;              hi = wo_hi;  lo = wo_lo;  K = 256; base = 160; }
    else if (blk < 224) { W = w1;              hi = w1a_hi; lo = w1a_lo; K = 256; base = 192; }
    else                { W = w1 + 256 * 256;  hi = w1b_hi; lo = w1b_lo; K = 256; base = 224; }
    int t = (blk - base) * 256 + threadIdx.x;
    int n = t & 255, k8 = t >> 8;
    short8 h8, l8;
#pragma unroll
    for (int j = 0; j < 8; ++j) {
        float wvl = W[(size_t)(k8 * 8 + j) * 256 + n];
        uint16_t h = f2bf(wvl);
        h8[j] = (short)h;
        l8[j] = (short)f2bf(wvl - bf2f(h));
    }
    size_t bb = (size_t)(n >> 4) * (K >> 5) + (k8 >> 2);
    int inner = (k8 & 3) * 16 + (n & 15);
    ((short8*)hi)[bb * 64 + inner] = h8;
    ((short8*)lo)[bb * 64 + inner] = l8;
}

// ---------------- split-bf16 MFMA core: 16x32 wave tile, depth-2 rolling prefetch ----------------
template<int KB>
__device__ __forceinline__ void mm_core(const short8* __restrict__ pAh, const short8* __restrict__ pAl,
                                        const short8* __restrict__ pBh0, const short8* __restrict__ pBl0,
                                        const short8* __restrict__ pBh1, const short8* __restrict__ pBl1,
                                        f32x4& acc0, f32x4& acc1) {
    short8 ah[3], al[3], bh0[3], bl0[3], bh1[3], bl1[3];
#pragma unroll
    for (int i = 0; i < 2; ++i) {
        int off = i * 64;
        ah[i] = pAh[off];  al[i] = pAl[off];
        bh0[i] = pBh0[off]; bl0[i] = pBl0[off];
        bh1[i] = pBh1[off]; bl1[i] = pBl1[off];
    }
#pragma unroll
    for (int ks = 0; ks < KB; ++ks) {
        int cur = ks % 3;
        if (ks + 2 < KB) {
            int pre = (ks + 2) % 3, off = (ks + 2) * 64;
            ah[pre] = pAh[off];  al[pre] = pAl[off];
            bh0[pre] = pBh0[off]; bl0[pre] = pBl0[off];
            bh1[pre] = pBh1[off]; bl1[pre] = pBl1[off];
        }
        acc0 = __builtin_amdgcn_mfma_f32_16x16x32_bf16(ah[cur], bh0[cur], acc0, 0, 0, 0);
        acc0 = __builtin_amdgcn_mfma_f32_16x16x32_bf16(ah[cur], bl0[cur], acc0, 0, 0, 0);
        acc0 = __builtin_amdgcn_mfma_f32_16x16x32_bf16(al[cur], bh0[cur], acc0, 0, 0, 0);
        acc1 = __builtin_amdgcn_mfma_f32_16x16x32_bf16(ah[cur], bh1[cur], acc1, 0, 0, 0);
        acc1 = __builtin_amdgcn_mfma_f32_16x16x32_bf16(ah[cur], bl1[cur], acc1, 0, 0, 0);
        acc1 = __builtin_amdgcn_mfma_f32_16x16x32_bf16(al[cur], bh1[cur], acc1, 0, 0, 0);
    }
}

__device__ __forceinline__ void epi_store(f32x4 acc, int row0, int col, int N,
                                          float* __restrict__ Cf, short* __restrict__ Chi,
                                          short* __restrict__ Clo,
                                          const float* __restrict__ bias, int act) {
#pragma unroll
    for (int r = 0; r < 4; ++r) {
        int row = row0 + r;
        float v2 = acc[r];
        if (bias) v2 += bias[(size_t)(row / 50) * N + col];
        if (act)  v2 = gelu_f(v2);
        if (Cf) Cf[(size_t)row * N + col] = v2;
        if (Chi) {
            uint16_t h = f2bf(v2);
            size_t ad = swzA(row, col, 256);
            Chi[ad] = (short)h;
            Clo[ad] = (short)f2bf(v2 - bf2f(h));
        }
    }
}

// single GEMM: grid (M/64, N/32); wave = 16 rows x 32 cols (2 n-strips)
template<int KB>
__global__ __launch_bounds__(256) void gemm_one(const short8* __restrict__ Ah,
                                                const short8* __restrict__ Al,
                                                const short8* __restrict__ Bh,
                                                const short8* __restrict__ Bl,
                                                float* __restrict__ Cf,
                                                short* __restrict__ Chi,
                                                short* __restrict__ Clo,
                                                const float* __restrict__ bias,
                                                int act) {
    int lane = threadIdx.x & 63;
    int wv   = threadIdx.x >> 6;
    int ms   = blockIdx.x * 4 + wv;
    int ns0  = blockIdx.y * 2;
    const short8* pAh  = Ah + (size_t)ms  * KB * 64 + lane;
    const short8* pAl  = Al + (size_t)ms  * KB * 64 + lane;
    const short8* pBh0 = Bh + (size_t)ns0 * KB * 64 + lane;
    const short8* pBl0 = Bl + (size_t)ns0 * KB * 64 + lane;
    const short8* pBh1 = pBh0 + (size_t)KB * 64;
    const short8* pBl1 = pBl0 + (size_t)KB * 64;
    f32x4 acc0 = {0.f,0.f,0.f,0.f}, acc1 = {0.f,0.f,0.f,0.f};
    mm_core<KB>(pAh, pAl, pBh0, pBl0, pBh1, pBl1, acc0, acc1);
    int row0 = ms * 16 + (lane >> 4) * 4;
    int cin  = lane & 15;
    epi_store(acc0, row0, ns0 * 16 + cin,      256, Cf, Chi, Clo, bias, act);
    epi_store(acc1, row0, (ns0 + 1) * 16 + cin, 256, Cf, Chi, Clo, bias, act);
}

// fused q/k/v: grid (150, 24); matrix = blockIdx.y>>3, n-strip-pair = blockIdx.y&7
__global__ __launch_bounds__(256) void gemm_qkv(const short8* __restrict__ Ah,
                                                const short8* __restrict__ Al,
                                                const short8* __restrict__ Bhq, const short8* __restrict__ Blq,
                                                const short8* __restrict__ Bhk, const short8* __restrict__ Blk,
                                                const short8* __restrict__ Bhv, const short8* __restrict__ Blv,
                                                float* __restrict__ q, float* __restrict__ k,
                                                float* __restrict__ v) {
    int lane = threadIdx.x & 63;
    int wv   = threadIdx.x >> 6;
    int ms   = blockIdx.x * 4 + wv;
    int sel  = blockIdx.y >> 3;
    int ns0  = (blockIdx.y & 7) * 2;
    const short8* Bh = (sel == 0) ? Bhq : (sel == 1) ? Bhk : Bhv;
    const short8* Bl = (sel == 0) ? Blq : (sel == 1) ? Blk : Blv;
    float* C = (sel == 0) ? q : (sel == 1) ? k : v;
    const short8* pAh  = Ah + (size_t)ms  * 8 * 64 + lane;
    const short8* pAl  = Al + (size_t)ms  * 8 * 64 + lane;
    const short8* pBh0 = Bh + (size_t)ns0 * 8 * 64 + lane;
    const short8* pBl0 = Bl + (size_t)ns0 * 8 * 64 + lane;
    const short8* pBh1 = pBh0 + 8 * 64;
    const short8* pBl1 = pBl0 + 8 * 64;
    f32x4 acc0 = {0.f,0.f,0.f,0.f}, acc1 = {0.f,0.f,0.f,0.f};
    mm_core<8>(pAh, pAl, pBh0, pBl0, pBh1, pBl1, acc0, acc1);
    int row0 = ms * 16 + (lane >> 4) * 4;
    int cin  = lane & 15;
    epi_store(acc0, row0, ns0 * 16 + cin,      256, C, nullptr, nullptr, nullptr, 0);
    epi_store(acc1, row0, (ns0 + 1) * 16 + cin, 256, C, nullptr, nullptr, nullptr, 0);
}

// ---------------- attention: one block per (batch, head); 2x2-blocked QK^T, float4 PV ----------------
__global__ __launch_bounds__(256) void attn_kernel(const float* __restrict__ q,
                                                   const float* __restrict__ k,
                                                   const float* __restrict__ v,
                                                   short* __restrict__ aoh,
                                                   short* __restrict__ aol) {
    __shared__ float sQ[NTOK * 132];
    __shared__ float sK[NTOK * 132];
    __shared__ float sS[NTOK * 51];
    int blk = blockIdx.x;
    int b = blk >> 1, h = blk & 1;
    const size_t base = (size_t)b * NTOK * C_DIM + h * HD;
    int tid = threadIdx.x;
    for (int idx = tid; idx < 1600; idx += 256) {
        int r = idx >> 5, c = (idx & 31) * 4;
        *(float4*)&sQ[r * 132 + c] = *(const float4*)(q + base + (size_t)r * C_DIM + c);
        *(float4*)&sK[r * 132 + c] = *(const float4*)(k + base + (size_t)r * C_DIM + c);
    }
    __syncthreads();
    for (int e = tid; e < 625; e += 256) {    // 25x25 quads of 2x2 dots
        int i2 = e / 25, j2 = e - i2 * 25;
        int i = i2 * 2, j = j2 * 2;
        const float* qi0 = &sQ[i * 132];
        const float* qi1 = qi0 + 132;
        const float* kj0 = &sK[j * 132];
        const float* kj1 = kj0 + 132;
        float4 a00 = {0,0,0,0}, a01 = {0,0,0,0}, a10 = {0,0,0,0}, a11 = {0,0,0,0};
#pragma unroll
        for (int t = 0; t < 32; ++t) {
            float4 q0 = *(const float4*)&qi0[t * 4];
            float4 q1 = *(const float4*)&qi1[t * 4];
            float4 b0 = *(const float4*)&kj0[t * 4];
            float4 b1 = *(const float4*)&kj1[t * 4];
            a00.x = fmaf(q0.x, b0.x, a00.x); a00.y = fmaf(q0.y, b0.y, a00.y);
            a00.z = fmaf(q0.z, b0.z, a00.z); a00.w = fmaf(q0.w, b0.w, a00.w);
            a01.x = fmaf(q0.x, b1.x, a01.x); a01.y = fmaf(q0.y, b1.y, a01.y);
            a01.z = fmaf(q0.z, b1.z, a01.z); a01.w = fmaf(q0.w, b1.w, a01.w);
            a10.x = fmaf(q1.x, b0.x, a10.x); a10.y = fmaf(q1.y, b0.y, a10.y);
            a10.z = fmaf(q1.z, b0.z, a10.z); a10.w = fmaf(q1.w, b0.w, a10.w);
            a11.x = fmaf(q1.x, b1.x, a11.x); a11.y = fmaf(q1.y, b1.y, a11.y);
            a11.z = fmaf(q1.z, b1.z, a11.z); a11.w = fmaf(q1.w, b1.w, a11.w);
        }
        const float sc = 0.08838834764831845f;   // 1/sqrt(128)
        sS[i * 51 + j]           = (a00.x + a00.y + a00.z + a00.w) * sc;
        sS[i * 51 + j + 1]       = (a01.x + a01.y + a01.z + a01.w) * sc;
        sS[(i + 1) * 51 + j]     = (a10.x + a10.y + a10.z + a10.w) * sc;
        sS[(i + 1) * 51 + j + 1] = (a11.x + a11.y + a11.z + a11.w) * sc;
    }
    __syncthreads();
    for (int idx = tid; idx < 1600; idx += 256) {   // overwrite sQ with v
        int r = idx >> 5, c = (idx & 31) * 4;
        *(float4*)&sQ[r * 132 + c] = *(const float4*)(v + base + (size_t)r * C_DIM + c);
    }
    if (tid < NTOK) {
        float* row = &sS[tid * 51];
        float m = row[0];
        for (int j = 1; j < NTOK; ++j) m = fmaxf(m, row[j]);
        float sum = 0.f;
        for (int j = 0; j < NTOK; ++j) { float e2 = expf(row[j] - m); row[j] = e2; sum += e2; }
        float inv = 1.0f / sum;
        for (int j = 0; j < NTOK; ++j) row[j] *= inv;
    }
    __syncthreads();
    for (int e = tid; e < 1600; e += 256) {   // PV: 4 d's per thread
        int i = e >> 5, d4 = (e & 31) * 4;
        const float* srow = &sS[i * 51];
        float4 acc = {0,0,0,0};
#pragma unroll
        for (int j = 0; j < NTOK; ++j) {
            float w = srow[j];
            float4 v4 = *(const float4*)&sQ[j * 132 + d4];
            acc.x = fmaf(w, v4.x, acc.x); acc.y = fmaf(w, v4.y, acc.y);
            acc.z = fmaf(w, v4.z, acc.z); acc.w = fmaf(w, v4.w, acc.w);
        }
        int row = b * NTOK + i;
        float vals[4] = {acc.x, acc.y, acc.z, acc.w};
#pragma unroll
        for (int c = 0; c < 4; ++c) {
            int col = h * HD + d4 + c;
            uint16_t hh = f2bf(vals[c]);
            size_t ad = swzA(row, col, 256);
            aoh[ad] = (short)hh;
            aol[ad] = (short)f2bf(vals[c] - bf2f(hh));
        }
    }
}

// ---------------- mean over 50 tokens -> swizzled hi/lo bf16 ----------------
__global__ __launch_bounds__(256) void mean50(const float* __restrict__ h2,
                                              short* __restrict__ gh,
                                              short* __restrict__ gl) {
    int b = blockIdx.x, c = threadIdx.x;
    float s = 0.f;
    for (int n = 0; n < NTOK; ++n) s += h2[((size_t)b * NTOK + n) * C_DIM + c];
    float g = s / 50.0f;
    uint16_t h = f2bf(g);
    size_t ad = swzA(b, c, 256);
    gh[ad] = (short)h;
    gl[ad] = (short)f2bf(g - bf2f(h));
}

// ---------------- pred = tanh(h3 @ w2): one wave per row ----------------
__global__ __launch_bounds__(256) void matvec_tanh(const float* __restrict__ h3,
                                                   const float* __restrict__ w2,
                                                   float* __restrict__ pred) {
    int row  = blockIdx.x * 4 + (threadIdx.x >> 6);
    int lane = threadIdx.x & 63;
    const float* rp = h3 + (size_t)row * C_DIM;
    float4 a = *(const float4*)(rp + lane * 4);
    float4 w = *(const float4*)(w2 + lane * 4);
    float s = a.x * w.x + a.y * w.y + a.z * w.z + a.w * w.w;
#pragma unroll
    for (int off = 32; off; off >>= 1) s += __shfl_xor(s, off);
    if (lane == 0) pred[row] = tanhf(s);
}

// ---------------- JAX threefry2x32 with key (0,1) ----------------
__device__ __forceinline__ uint32_t rotl32(uint32_t x, int r) {
    return (x << r) | (x >> (32 - r));
}
__device__ __forceinline__ void threefry01(uint32_t& x0, uint32_t& x1) {
    const uint32_t ks0 = 0u, ks1 = 1u, ks2 = 0x1BD11BDBu;
    x0 += ks0; x1 += ks1;
#define TFR(r) { x0 += x1; x1 = rotl32(x1, r); x1 ^= x0; }
    TFR(13) TFR(15) TFR(26) TFR(6)  x0 += ks1; x1 += ks2 + 1u;
    TFR(17) TFR(29) TFR(16) TFR(24) x0 += ks2; x1 += ks0 + 2u;
    TFR(13) TFR(15) TFR(26) TFR(6)  x0 += ks0; x1 += ks1 + 3u;
    TFR(17) TFR(29) TFR(16) TFR(24) x0 += ks1; x1 += ks2 + 4u;
    TFR(13) TFR(15) TFR(26) TFR(6)  x0 += ks2; x1 += ks0 + 5u;
#undef TFR
}

__device__ __forceinline__ float erfinv_xla(float x) {
    float w = -log1pf(-x * x);
    float p;
    if (w < 5.0f) {
        w -= 2.5f;
        p = 2.81022636e-08f;
        p = fmaf(p, w, 3.43273939e-07f);
        p = fmaf(p, w, -3.5233877e-06f);
        p = fmaf(p, w, -4.39150654e-06f);
        p = fmaf(p, w, 0.00021858087f);
        p = fmaf(p, w, -0.00125372503f);
        p = fmaf(p, w, -0.00417768164f);
        p = fmaf(p, w, 0.246640727f);
        p = fmaf(p, w, 1.50140941f);
    } else {
        w = sqrtf(w) - 3.0f;
        p = -0.000200214257f;
        p = fmaf(p, w, 0.000100950558f);
        p = fmaf(p, w, 0.00134934322f);
        p = fmaf(p, w, -0.00367342844f);
        p = fmaf(p, w, 0.00573950773f);
        p = fmaf(p, w, -0.0076224613f);
        p = fmaf(p, w, 0.00943887047f);
        p = fmaf(p, w, 1.00167406f);
        p = fmaf(p, w, 2.83297682f);
    }
    return p * x;
}

__device__ __forceinline__ float bits_to_normal(uint32_t bits) {
    float f = __uint_as_float((bits >> 9) | 0x3f800000u) - 1.0f;
    float u = f * 2.0f + (-0.99999994039535522461f);
    u = fmaxf(-0.99999994039535522461f, u);
    return 1.4142135623730951f * erfinv_xla(u);
}

// Partitionable threefry; wave-uniform binary search for 12th-largest key + exact ties.
__global__ __launch_bounds__(256) void topk_kernel(const float* __restrict__ pred,
                                                   int* __restrict__ counts) {
    int wid  = (blockIdx.x * 256 + threadIdx.x) >> 6;
    int lane = threadIdx.x & 63;
    int b = wid / NSAMP;
    int s = wid - b * NSAMP;
    uint32_t lo = (uint32_t)((b * NSAMP + s) * NSPA + lane);
    uint32_t x0 = 0u, x1 = lo;
    threefry01(x0, x1);
    float n = bits_to_normal(x0 ^ x1);
    float sc = (lane < NSPA) ? pred[b * NTOK + 2 + lane] : 0.f;
    float v  = (lane < NSPA) ? sc + n * 0.05f : -INFINITY;

    uint32_t vb   = __float_as_uint(v);
    uint32_t mono = (vb & 0x80000000u) ? ~vb : (vb | 0x80000000u);
    uint32_t t = 0;
#pragma unroll
    for (int bit = 31; bit >= 0; --bit) {
        uint32_t c = t | (1u << bit);
        unsigned long long m = __ballot(mono >= c);
        if (__popcll(m) >= TOPKK) t = c;
    }
    unsigned long long mgt = __ballot(mono > t);
    unsigned long long meq = __ballot(mono == t);
    int r = TOPKK - __popcll(mgt);
    unsigned long long below = (1ull << lane) - 1ull;
    bool sel = (mono > t) || ((mono == t) && (__popcll(meq & below) < r));
    sel = sel && (lane < NSPA);
    unsigned long long mask = __ballot(sel);
    if (sel) {
        int kpos = __popcll(mask & below);
        atomicAdd(&counts[((size_t)b * TOPKK + kpos) * NSPA + lane], 1);
    }
}

// ---------------- output assembly ----------------
__global__ __launch_bounds__(256) void select_out(const float* __restrict__ x,
                                                  const int* __restrict__ counts,
                                                  float* __restrict__ out) {
    int row = blockIdx.x;
    int b = row / 14, k = row - b * 14;
    int d = threadIdx.x;
    if (k < 2) {
        out[(size_t)row * D_EMB + d]       = x[((size_t)(b * NTOK + k)) * D_EMB + d];
        out[(size_t)row * D_EMB + d + 256] = x[((size_t)(b * NTOK + k)) * D_EMB + d + 256];
    } else {
        int kk = k - 2;
        const int* cnt = counts + ((size_t)b * TOPKK + kk) * NSPA;
        __shared__ int sc[NSPA];
        if (d < NSPA) sc[d] = cnt[d];
        __syncthreads();
        float a0 = 0.f, a1 = 0.f;
        for (int l = 0; l < NSPA; ++l) {
            int c = sc[l];
            if (c) {
                float w = (float)c / 500.0f;
                const float* xr = x + ((size_t)(b * NTOK + 2 + l)) * D_EMB;
                a0 = fmaf(w, xr[d], a0);
                a1 = fmaf(w, xr[d + 256], a1);
            }
        }
        out[(size_t)row * D_EMB + d]       = a0;
        out[(size_t)row * D_EMB + d + 256] = a1;
    }
}

extern "C" void kernel_launch(void* const* d_in, const int* in_sizes, int n_in,
                              void* d_out, int out_size, void* d_ws, size_t ws_size,
                              hipStream_t stream) {
    const float* x    = (const float*)d_in[0];
    const float* ln_g = (const float*)d_in[1];
    const float* ln_b = (const float*)d_in[2];
    const float* w_in = (const float*)d_in[3];
    const float* wq   = (const float*)d_in[4];
    const float* wk   = (const float*)d_in[5];
    const float* wv   = (const float*)d_in[6];
    const float* wo   = (const float*)d_in[7];
    const float* w1   = (const float*)d_in[8];
    const float* w2   = (const float*)d_in[9];
    float* out = (float*)d_out;

    char* W = (char*)d_ws;
    short* xn_hi  = (short*)(W + 0);            // 9,830,400 B
    short* xn_lo  = (short*)(W + 9830400);      // 9,830,400 B
    //   region reuse after xn is dead:
    short* ao_hi  = (short*)(W + 0);            // 4,915,200
    short* ao_lo  = (short*)(W + 4915200);      // 4,915,200
    short* h2_hi  = (short*)(W + 9830400);      // 4,915,200
    short* h2_lo  = (short*)(W + 14745600);     // 4,915,200
    short* h1_hi  = (short*)(W + 19660800);     // 4,915,200
    short* h1_lo  = (short*)(W + 24576000);     // 4,915,200
    float* h3     = (float*)(W + 19660800);     // 9,830,400 (aliases h1 after qkv)
    float* q      = (float*)(W + 29491200);     // 9,830,400
    float* h2f    = (float*)(W + 29491200);     // aliases q after attn
    float* k      = (float*)(W + 39321600);     // 9,830,400
    float* v      = (float*)(W + 49152000);     // 9,830,400
    short* win_hi = (short*)(W + 58982400);     // 262,144
    short* win_lo = (short*)(W + 59244544);
    short* wq_hi  = (short*)(W + 59506688);     // 131,072 each from here
    short* wq_lo  = (short*)(W + 59637760);
    short* wk_hi  = (short*)(W + 59768832);
    short* wk_lo  = (short*)(W + 59899904);
    short* wv_hi  = (short*)(W + 60030976);
    short* wv_lo  = (short*)(W + 60162048);
    short* wo_hi  = (short*)(W + 60293120);
    short* wo_lo  = (short*)(W + 60424192);
    short* w1a_hi = (short*)(W + 60555264);
    short* w1a_lo = (short*)(W + 60686336);
    short* w1b_hi = (short*)(W + 60817408);
    short* w1b_lo = (short*)(W + 60948480);
    short* gm_hi  = (short*)(W + 61079552);     // 98,304
    short* gm_lo  = (short*)(W + 61177856);     // 98,304
    float* gw     = (float*)(W + 61276160);     // 196,608
    float* pred   = (float*)(W + 61472768);     // 38,400
    int*   counts = (int*)  (W + 61511168);     // 442,368

    // 1. LN -> swizzled xn (K=512 layout); weights swizzled in one launch
    ln_kernel<<<ROWS / 4, 256, 0, stream>>>(x, ln_g, ln_b, xn_hi, xn_lo);
    swz_all<<<256, 256, 0, stream>>>(w_in, wq, wk, wv, wo, w1,
        win_hi, win_lo, wq_hi, wq_lo, wk_hi, wk_lo, wv_hi, wv_lo,
        wo_hi, wo_lo, w1a_hi, w1a_lo, w1b_hi, w1b_lo);
    // 2. h1 = gelu(xn @ w_in)  (swizzled out only)
    gemm_one<16><<<dim3(150, 8), 256, 0, stream>>>((const short8*)xn_hi, (const short8*)xn_lo,
        (const short8*)win_hi, (const short8*)win_lo, nullptr, h1_hi, h1_lo, nullptr, 1);
    // 3. fused q/k/v = h1 @ w{q,k,v}
    gemm_qkv<<<dim3(150, 24), 256, 0, stream>>>((const short8*)h1_hi, (const short8*)h1_lo,
        (const short8*)wq_hi, (const short8*)wq_lo, (const short8*)wk_hi, (const short8*)wk_lo,
        (const short8*)wv_hi, (const short8*)wv_lo, q, k, v);
    // 4. attention -> swizzled ao (xn region now dead)
    attn_kernel<<<B2 * 2, 256, 0, stream>>>(q, k, v, ao_hi, ao_lo);
    // 5. h2 = ao @ wo  (fp32 into old q + swizzled)
    gemm_one<8><<<dim3(150, 8), 256, 0, stream>>>((const short8*)ao_hi, (const short8*)ao_lo,
        (const short8*)wo_hi, (const short8*)wo_lo, h2f, h2_hi, h2_lo, nullptr, 0);
    // 6. gmean (swizzled)
    mean50<<<B2, 256, 0, stream>>>(h2f, gm_hi, gm_lo);
    // 7. gw = gmean @ w1[256:]
    gemm_one<8><<<dim3(3, 8), 256, 0, stream>>>((const short8*)gm_hi, (const short8*)gm_lo,
        (const short8*)w1b_hi, (const short8*)w1b_lo, gw, nullptr, nullptr, nullptr, 0);
    // 8. h3 = gelu(h2 @ w1[:256] + gw-bias)
    gemm_one<8><<<dim3(150, 8), 256, 0, stream>>>((const short8*)h2_hi, (const short8*)h2_lo,
        (const short8*)w1a_hi, (const short8*)w1a_lo, h3, nullptr, nullptr, gw, 1);
    // 9. scores, topk, output
    matvec_tanh<<<ROWS / 4, 256, 0, stream>>>(h3, w2, pred);
    hipMemsetAsync(counts, 0, (size_t)B2 * TOPKK * NSPA * sizeof(int), stream);
    topk_kernel<<<B2 * NSAMP / 4, 256, 0, stream>>>(pred, counts);
    select_out<<<B2 * 14, 256, 0, stream>>>(x, counts, out);
}

// Round 7
// 297.373 us; speedup vs baseline: 1.5725x; 1.0547x over previous
//
#include <hip/hip_runtime.h>
#include <stdint.h>

// ---------------- problem constants ----------------
#define B2      192          // 16 * MAX_FRAMES
#define NTOK    50           // tokens per frame-batch
#define ROWS    9600         // B2 * NTOK
#define D_EMB   512
#define C_DIM   256
#define HD      128          // head dim
#define NSAMP   500
#define TOPKK   12
#define NSPA    48           // 50 - SEL_DIM

typedef short short8 __attribute__((ext_vector_type(8)));
typedef float f32x4  __attribute__((ext_vector_type(4)));

__device__ __forceinline__ float gelu_f(float x) {
    return 0.5f * x * (1.0f + erff(x * 0.7071067811865476f));
}
__device__ __forceinline__ uint16_t f2bf(float x) {   // RNE fp32->bf16
    uint32_t u = __float_as_uint(x);
    return (uint16_t)((u + 0x7fffu + ((u >> 16) & 1u)) >> 16);
}
__device__ __forceinline__ float bf2f(uint16_t b) {
    return __uint_as_float(((uint32_t)b) << 16);
}
// swizzled A-operand halfword index (frag-contiguous MFMA layout)
__device__ __forceinline__ size_t swzA(int m, int k, int K) {
    return ((size_t)(m >> 4) * (K >> 5) + (k >> 5)) * 512
         + (size_t)((((k >> 3) & 3) * 16 + (m & 15)) * 8 + (k & 7));
}

// ---------------- fused LN + weight swizzle (one launch) ----------------
// blocks 0..2399: LayerNorm rows; blocks 2400..2655: weight swizzle.
__global__ __launch_bounds__(256) void prep_kernel(const float* __restrict__ x,
                                                   const float* __restrict__ g,
                                                   const float* __restrict__ b,
                                                   short* __restrict__ xh,
                                                   short* __restrict__ xl,
                                                   const float* __restrict__ w_in, const float* __restrict__ wq,
                                                   const float* __restrict__ wk, const float* __restrict__ wv,
                                                   const float* __restrict__ wo, const float* __restrict__ w1,
                                                   short* win_hi, short* win_lo, short* wq_hi, short* wq_lo,
                                                   short* wk_hi, short* wk_lo, short* wv_hi, short* wv_lo,
                                                   short* wo_hi, short* wo_lo, short* w1a_hi, short* w1a_lo,
                                                   short* w1b_hi, short* w1b_lo) {
    if (blockIdx.x < 2400) {
        int row  = blockIdx.x * 4 + (threadIdx.x >> 6);
        int lane = threadIdx.x & 63;
        const float* rp = x + (size_t)row * D_EMB;
        float4 v0 = *(const float4*)(rp + lane * 8);
        float4 v1 = *(const float4*)(rp + lane * 8 + 4);
        float s  = v0.x + v0.y + v0.z + v0.w + v1.x + v1.y + v1.z + v1.w;
        float s2 = v0.x*v0.x + v0.y*v0.y + v0.z*v0.z + v0.w*v0.w
                 + v1.x*v1.x + v1.y*v1.y + v1.z*v1.z + v1.w*v1.w;
#pragma unroll
        for (int off = 32; off; off >>= 1) {
            s  += __shfl_xor(s,  off);
            s2 += __shfl_xor(s2, off);
        }
        float mu  = s / 512.0f;
        float var = s2 / 512.0f - mu * mu;
        float inv = 1.0f / sqrtf(var + 1e-5f);
        const float* gp = g + lane * 8;
        const float* bp = b + lane * 8;
        float o[8];
        o[0]=(v0.x-mu)*inv*gp[0]+bp[0]; o[1]=(v0.y-mu)*inv*gp[1]+bp[1];
        o[2]=(v0.z-mu)*inv*gp[2]+bp[2]; o[3]=(v0.w-mu)*inv*gp[3]+bp[3];
        o[4]=(v1.x-mu)*inv*gp[4]+bp[4]; o[5]=(v1.y-mu)*inv*gp[5]+bp[5];
        o[6]=(v1.z-mu)*inv*gp[6]+bp[6]; o[7]=(v1.w-mu)*inv*gp[7]+bp[7];
        short8 h8, l8;
#pragma unroll
        for (int j = 0; j < 8; ++j) {
            uint16_t h = f2bf(o[j]);
            h8[j] = (short)h;
            l8[j] = (short)f2bf(o[j] - bf2f(h));
        }
        size_t blk = (size_t)(row >> 4) * 16 + (lane >> 2);
        int inner  = (lane & 3) * 16 + (row & 15);
        ((short8*)xh)[blk * 64 + inner] = h8;
        ((short8*)xl)[blk * 64 + inner] = l8;
    } else {
        int blk = blockIdx.x - 2400;
        const float* W; short *hi, *lo; int K, base;
        if      (blk <  64) { W = w_in;            hi = win_hi; lo = win_lo; K = 512; base = 0;   }
        else if (blk <  96) { W = wq;              hi = wq_hi;  lo = wq_lo;  K = 256; base = 64;  }
        else if (blk < 128) { W = wk;              hi = wk_hi;  lo = wk_lo;  K = 256; base = 96;  }
        else if (blk < 160) { W = wv;              hi = wv_hi;  lo = wv_lo;  K = 256; base = 128; }
        else if (blk < 192) { W = wo;              hi = wo_hi;  lo = wo_lo;  K = 256; base = 160; }
        else if (blk < 224) { W = w1;              hi = w1a_hi; lo = w1a_lo; K = 256; base = 192; }
        else                { W = w1 + 256 * 256;  hi = w1b_hi; lo = w1b_lo; K = 256; base = 224; }
        int t = (blk - base) * 256 + threadIdx.x;
        int n = t & 255, k8 = t >> 8;
        short8 h8, l8;
#pragma unroll
        for (int j = 0; j < 8; ++j) {
            float wvl = W[(size_t)(k8 * 8 + j) * 256 + n];
            uint16_t h = f2bf(wvl);
            h8[j] = (short)h;
            l8[j] = (short)f2bf(wvl - bf2f(h));
        }
        size_t bb = (size_t)(n >> 4) * (K >> 5) + (k8 >> 2);
        int inner = (k8 & 3) * 16 + (n & 15);
        ((short8*)hi)[bb * 64 + inner] = h8;
        ((short8*)lo)[bb * 64 + inner] = l8;
    }
}

// ---------------- split-bf16 MFMA core: 16x32 wave tile, depth-2 rolling prefetch ----------------
template<int KB>
__device__ __forceinline__ void mm_core(const short8* __restrict__ pAh, const short8* __restrict__ pAl,
                                        const short8* __restrict__ pBh0, const short8* __restrict__ pBl0,
                                        const short8* __restrict__ pBh1, const short8* __restrict__ pBl1,
                                        f32x4& acc0, f32x4& acc1) {
    short8 ah[3], al[3], bh0[3], bl0[3], bh1[3], bl1[3];
#pragma unroll
    for (int i = 0; i < 2; ++i) {
        int off = i * 64;
        ah[i] = pAh[off];  al[i] = pAl[off];
        bh0[i] = pBh0[off]; bl0[i] = pBl0[off];
        bh1[i] = pBh1[off]; bl1[i] = pBl1[off];
    }
#pragma unroll
    for (int ks = 0; ks < KB; ++ks) {
        int cur = ks % 3;
        if (ks + 2 < KB) {
            int pre = (ks + 2) % 3, off = (ks + 2) * 64;
            ah[pre] = pAh[off];  al[pre] = pAl[off];
            bh0[pre] = pBh0[off]; bl0[pre] = pBl0[off];
            bh1[pre] = pBh1[off]; bl1[pre] = pBl1[off];
        }
        acc0 = __builtin_amdgcn_mfma_f32_16x16x32_bf16(ah[cur], bh0[cur], acc0, 0, 0, 0);
        acc0 = __builtin_amdgcn_mfma_f32_16x16x32_bf16(ah[cur], bl0[cur], acc0, 0, 0, 0);
        acc0 = __builtin_amdgcn_mfma_f32_16x16x32_bf16(al[cur], bh0[cur], acc0, 0, 0, 0);
        acc1 = __builtin_amdgcn_mfma_f32_16x16x32_bf16(ah[cur], bh1[cur], acc1, 0, 0, 0);
        acc1 = __builtin_amdgcn_mfma_f32_16x16x32_bf16(ah[cur], bl1[cur], acc1, 0, 0, 0);
        acc1 = __builtin_amdgcn_mfma_f32_16x16x32_bf16(al[cur], bh1[cur], acc1, 0, 0, 0);
    }
}

__device__ __forceinline__ void epi_store(f32x4 acc, int row0, int col, int N,
                                          float* __restrict__ Cf, short* __restrict__ Chi,
                                          short* __restrict__ Clo,
                                          const float* __restrict__ bias, int act) {
#pragma unroll
    for (int r = 0; r < 4; ++r) {
        int row = row0 + r;
        float v2 = acc[r];
        if (bias) v2 += bias[(size_t)(row / 50) * N + col];
        if (act)  v2 = gelu_f(v2);
        if (Cf) Cf[(size_t)row * N + col] = v2;
        if (Chi) {
            uint16_t h = f2bf(v2);
            size_t ad = swzA(row, col, 256);
            Chi[ad] = (short)h;
            Clo[ad] = (short)f2bf(v2 - bf2f(h));
        }
    }
}

// single GEMM: grid (M/64, N/32); wave = 16 rows x 32 cols (2 n-strips)
template<int KB>
__global__ __launch_bounds__(256) void gemm_one(const short8* __restrict__ Ah,
                                                const short8* __restrict__ Al,
                                                const short8* __restrict__ Bh,
                                                const short8* __restrict__ Bl,
                                                float* __restrict__ Cf,
                                                short* __restrict__ Chi,
                                                short* __restrict__ Clo,
                                                const float* __restrict__ bias,
                                                int act) {
    int lane = threadIdx.x & 63;
    int wv   = threadIdx.x >> 6;
    int ms   = blockIdx.x * 4 + wv;
    int ns0  = blockIdx.y * 2;
    const short8* pAh  = Ah + (size_t)ms  * KB * 64 + lane;
    const short8* pAl  = Al + (size_t)ms  * KB * 64 + lane;
    const short8* pBh0 = Bh + (size_t)ns0 * KB * 64 + lane;
    const short8* pBl0 = Bl + (size_t)ns0 * KB * 64 + lane;
    const short8* pBh1 = pBh0 + (size_t)KB * 64;
    const short8* pBl1 = pBl0 + (size_t)KB * 64;
    f32x4 acc0 = {0.f,0.f,0.f,0.f}, acc1 = {0.f,0.f,0.f,0.f};
    mm_core<KB>(pAh, pAl, pBh0, pBl0, pBh1, pBl1, acc0, acc1);
    int row0 = ms * 16 + (lane >> 4) * 4;
    int cin  = lane & 15;
    epi_store(acc0, row0, ns0 * 16 + cin,      256, Cf, Chi, Clo, bias, act);
    epi_store(acc1, row0, (ns0 + 1) * 16 + cin, 256, Cf, Chi, Clo, bias, act);
}

// fused q/k/v: grid (150, 24); matrix = blockIdx.y>>3, n-strip-pair = blockIdx.y&7
__global__ __launch_bounds__(256) void gemm_qkv(const short8* __restrict__ Ah,
                                                const short8* __restrict__ Al,
                                                const short8* __restrict__ Bhq, const short8* __restrict__ Blq,
                                                const short8* __restrict__ Bhk, const short8* __restrict__ Blk,
                                                const short8* __restrict__ Bhv, const short8* __restrict__ Blv,
                                                float* __restrict__ q, float* __restrict__ k,
                                                float* __restrict__ v) {
    int lane = threadIdx.x & 63;
    int wv   = threadIdx.x >> 6;
    int ms   = blockIdx.x * 4 + wv;
    int sel  = blockIdx.y >> 3;
    int ns0  = (blockIdx.y & 7) * 2;
    const short8* Bh = (sel == 0) ? Bhq : (sel == 1) ? Bhk : Bhv;
    const short8* Bl = (sel == 0) ? Blq : (sel == 1) ? Blk : Blv;
    float* C = (sel == 0) ? q : (sel == 1) ? k : v;
    const short8* pAh  = Ah + (size_t)ms  * 8 * 64 + lane;
    const short8* pAl  = Al + (size_t)ms  * 8 * 64 + lane;
    const short8* pBh0 = Bh + (size_t)ns0 * 8 * 64 + lane;
    const short8* pBl0 = Bl + (size_t)ns0 * 8 * 64 + lane;
    const short8* pBh1 = pBh0 + 8 * 64;
    const short8* pBl1 = pBl0 + 8 * 64;
    f32x4 acc0 = {0.f,0.f,0.f,0.f}, acc1 = {0.f,0.f,0.f,0.f};
    mm_core<8>(pAh, pAl, pBh0, pBl0, pBh1, pBl1, acc0, acc1);
    int row0 = ms * 16 + (lane >> 4) * 4;
    int cin  = lane & 15;
    epi_store(acc0, row0, ns0 * 16 + cin,      256, C, nullptr, nullptr, nullptr, 0);
    epi_store(acc1, row0, (ns0 + 1) * 16 + cin, 256, C, nullptr, nullptr, nullptr, 0);
}

// ---------------- attention: one block per (batch, head); 2x2-blocked QK^T, float4 PV ----------------
__global__ __launch_bounds__(256) void attn_kernel(const float* __restrict__ q,
                                                   const float* __restrict__ k,
                                                   const float* __restrict__ v,
                                                   short* __restrict__ aoh,
                                                   short* __restrict__ aol) {
    __shared__ float sQ[NTOK * 132];
    __shared__ float sK[NTOK * 132];
    __shared__ float sS[NTOK * 51];
    int blk = blockIdx.x;
    int b = blk >> 1, h = blk & 1;
    const size_t base = (size_t)b * NTOK * C_DIM + h * HD;
    int tid = threadIdx.x;
    for (int idx = tid; idx < 1600; idx += 256) {
        int r = idx >> 5, c = (idx & 31) * 4;
        *(float4*)&sQ[r * 132 + c] = *(const float4*)(q + base + (size_t)r * C_DIM + c);
        *(float4*)&sK[r * 132 + c] = *(const float4*)(k + base + (size_t)r * C_DIM + c);
    }
    __syncthreads();
    for (int e = tid; e < 625; e += 256) {    // 25x25 quads of 2x2 dots
        int i2 = e / 25, j2 = e - i2 * 25;
        int i = i2 * 2, j = j2 * 2;
        const float* qi0 = &sQ[i * 132];
        const float* qi1 = qi0 + 132;
        const float* kj0 = &sK[j * 132];
        const float* kj1 = kj0 + 132;
        float4 a00 = {0,0,0,0}, a01 = {0,0,0,0}, a10 = {0,0,0,0}, a11 = {0,0,0,0};
#pragma unroll
        for (int t = 0; t < 32; ++t) {
            float4 q0 = *(const float4*)&qi0[t * 4];
            float4 q1 = *(const float4*)&qi1[t * 4];
            float4 b0 = *(const float4*)&kj0[t * 4];
            float4 b1 = *(const float4*)&kj1[t * 4];
            a00.x = fmaf(q0.x, b0.x, a00.x); a00.y = fmaf(q0.y, b0.y, a00.y);
            a00.z = fmaf(q0.z, b0.z, a00.z); a00.w = fmaf(q0.w, b0.w, a00.w);
            a01.x = fmaf(q0.x, b1.x, a01.x); a01.y = fmaf(q0.y, b1.y, a01.y);
            a01.z = fmaf(q0.z, b1.z, a01.z); a01.w = fmaf(q0.w, b1.w, a01.w);
            a10.x = fmaf(q1.x, b0.x, a10.x); a10.y = fmaf(q1.y, b0.y, a10.y);
            a10.z = fmaf(q1.z, b0.z, a10.z); a10.w = fmaf(q1.w, b0.w, a10.w);
            a11.x = fmaf(q1.x, b1.x, a11.x); a11.y = fmaf(q1.y, b1.y, a11.y);
            a11.z = fmaf(q1.z, b1.z, a11.z); a11.w = fmaf(q1.w, b1.w, a11.w);
        }
        const float sc = 0.08838834764831845f;   // 1/sqrt(128)
        sS[i * 51 + j]           = (a00.x + a00.y + a00.z + a00.w) * sc;
        sS[i * 51 + j + 1]       = (a01.x + a01.y + a01.z + a01.w) * sc;
        sS[(i + 1) * 51 + j]     = (a10.x + a10.y + a10.z + a10.w) * sc;
        sS[(i + 1) * 51 + j + 1] = (a11.x + a11.y + a11.z + a11.w) * sc;
    }
    __syncthreads();
    for (int idx = tid; idx < 1600; idx += 256) {   // overwrite sQ with v
        int r = idx >> 5, c = (idx & 31) * 4;
        *(float4*)&sQ[r * 132 + c] = *(const float4*)(v + base + (size_t)r * C_DIM + c);
    }
    if (tid < NTOK) {
        float* row = &sS[tid * 51];
        float m = row[0];
        for (int j = 1; j < NTOK; ++j) m = fmaxf(m, row[j]);
        float sum = 0.f;
        for (int j = 0; j < NTOK; ++j) { float e2 = expf(row[j] - m); row[j] = e2; sum += e2; }
        float inv = 1.0f / sum;
        for (int j = 0; j < NTOK; ++j) row[j] *= inv;
    }
    __syncthreads();
    for (int e = tid; e < 1600; e += 256) {   // PV: 4 d's per thread
        int i = e >> 5, d4 = (e & 31) * 4;
        const float* srow = &sS[i * 51];
        float4 acc = {0,0,0,0};
#pragma unroll
        for (int j = 0; j < NTOK; ++j) {
            float w = srow[j];
            float4 v4 = *(const float4*)&sQ[j * 132 + d4];
            acc.x = fmaf(w, v4.x, acc.x); acc.y = fmaf(w, v4.y, acc.y);
            acc.z = fmaf(w, v4.z, acc.z); acc.w = fmaf(w, v4.w, acc.w);
        }
        int row = b * NTOK + i;
        float vals[4] = {acc.x, acc.y, acc.z, acc.w};
#pragma unroll
        for (int c = 0; c < 4; ++c) {
            int col = h * HD + d4 + c;
            uint16_t hh = f2bf(vals[c]);
            size_t ad = swzA(row, col, 256);
            aoh[ad] = (short)hh;
            aol[ad] = (short)f2bf(vals[c] - bf2f(hh));
        }
    }
}

// ---------------- mean over 50 tokens -> swizzled hi/lo bf16 ----------------
__global__ __launch_bounds__(256) void mean50(const float* __restrict__ h2,
                                              short* __restrict__ gh,
                                              short* __restrict__ gl) {
    int b = blockIdx.x, c = threadIdx.x;
    float s = 0.f;
    for (int n = 0; n < NTOK; ++n) s += h2[((size_t)b * NTOK + n) * C_DIM + c];
    float g = s / 50.0f;
    uint16_t h = f2bf(g);
    size_t ad = swzA(b, c, 256);
    gh[ad] = (short)h;
    gl[ad] = (short)f2bf(g - bf2f(h));
}

// ---------------- pred = tanh(h3 @ w2): one wave per row ----------------
__global__ __launch_bounds__(256) void matvec_tanh(const float* __restrict__ h3,
                                                   const float* __restrict__ w2,
                                                   float* __restrict__ pred) {
    int row  = blockIdx.x * 4 + (threadIdx.x >> 6);
    int lane = threadIdx.x & 63;
    const float* rp = h3 + (size_t)row * C_DIM;
    float4 a = *(const float4*)(rp + lane * 4);
    float4 w = *(const float4*)(w2 + lane * 4);
    float s = a.x * w.x + a.y * w.y + a.z * w.z + a.w * w.w;
#pragma unroll
    for (int off = 32; off; off >>= 1) s += __shfl_xor(s, off);
    if (lane == 0) pred[row] = tanhf(s);
}

// ---------------- JAX threefry2x32 with key (0,1) ----------------
__device__ __forceinline__ uint32_t rotl32(uint32_t x, int r) {
    return (x << r) | (x >> (32 - r));
}
__device__ __forceinline__ void threefry01(uint32_t& x0, uint32_t& x1) {
    const uint32_t ks0 = 0u, ks1 = 1u, ks2 = 0x1BD11BDBu;
    x0 += ks0; x1 += ks1;
#define TFR(r) { x0 += x1; x1 = rotl32(x1, r); x1 ^= x0; }
    TFR(13) TFR(15) TFR(26) TFR(6)  x0 += ks1; x1 += ks2 + 1u;
    TFR(17) TFR(29) TFR(16) TFR(24) x0 += ks2; x1 += ks0 + 2u;
    TFR(13) TFR(15) TFR(26) TFR(6)  x0 += ks0; x1 += ks1 + 3u;
    TFR(17) TFR(29) TFR(16) TFR(24) x0 += ks1; x1 += ks2 + 4u;
    TFR(13) TFR(15) TFR(26) TFR(6)  x0 += ks2; x1 += ks0 + 5u;
#undef TFR
}

__device__ __forceinline__ float erfinv_xla(float x) {
    float w = -log1pf(-x * x);
    float p;
    if (w < 5.0f) {
        w -= 2.5f;
        p = 2.81022636e-08f;
        p = fmaf(p, w, 3.43273939e-07f);
        p = fmaf(p, w, -3.5233877e-06f);
        p = fmaf(p, w, -4.39150654e-06f);
        p = fmaf(p, w, 0.00021858087f);
        p = fmaf(p, w, -0.00125372503f);
        p = fmaf(p, w, -0.00417768164f);
        p = fmaf(p, w, 0.246640727f);
        p = fmaf(p, w, 1.50140941f);
    } else {
        w = sqrtf(w) - 3.0f;
        p = -0.000200214257f;
        p = fmaf(p, w, 0.000100950558f);
        p = fmaf(p, w, 0.00134934322f);
        p = fmaf(p, w, -0.00367342844f);
        p = fmaf(p, w, 0.00573950773f);
        p = fmaf(p, w, -0.0076224613f);
        p = fmaf(p, w, 0.00943887047f);
        p = fmaf(p, w, 1.00167406f);
        p = fmaf(p, w, 2.83297682f);
    }
    return p * x;
}

__device__ __forceinline__ float bits_to_normal(uint32_t bits) {
    float f = __uint_as_float((bits >> 9) | 0x3f800000u) - 1.0f;
    float u = f * 2.0f + (-0.99999994039535522461f);
    u = fmaxf(-0.99999994039535522461f, u);
    return 1.4142135623730951f * erfinv_xla(u);
}

// ---------------- topk, transposed: lane = sample, loop over 48 positions ----------------
// Each lane keeps a sorted-desc top-12 of keys (mono<<6 | 63-d) in registers.
// Two waves split d (0..23 / 24..47); halves merged via LDS + bitonic half-cleaner
// (12 max64 ops -- exact for distinct keys, and keys are unique by construction).
// Selection set & tie order identical to the ballot version => bit-identical counts.
__global__ __launch_bounds__(256) void topk_kernel(const float* __restrict__ pred,
                                                   int* __restrict__ counts) {
    __shared__ unsigned long long sK[128][13];   // partner half's 12 keys; +1 pad (2-way bank, free)
    int lane = threadIdx.x & 63;
    int wv   = threadIdx.x >> 6;
    int p    = wv >> 1;          // wave-pair 0/1 -> 64 samples each
    int hh   = wv & 1;           // half: 0 -> d=0..23, 1 -> d=24..47
    int g    = blockIdx.x * 128 + p * 64 + lane; // global sample id 0..95999
    int b    = g / NSAMP;
    int s    = g - b * NSAMP;
    uint32_t base = (uint32_t)((b * NSAMP + s) * NSPA);
    const float* sp = pred + b * NTOK + 2;

    unsigned long long list[TOPKK];
#pragma unroll
    for (int i = 0; i < TOPKK; ++i) list[i] = 0ull;   // 0 < any real key

    int d0 = hh * 24;
#pragma unroll 2
    for (int dd = 0; dd < 24; ++dd) {
        int d = d0 + dd;
        uint32_t x0 = 0u, x1 = base + (uint32_t)d;
        threefry01(x0, x1);
        float n  = bits_to_normal(x0 ^ x1);
        float v  = sp[d] + n * 0.05f;
        uint32_t vb   = __float_as_uint(v);
        uint32_t mono = (vb & 0x80000000u) ? ~vb : (vb | 0x80000000u);
        unsigned long long key = ((unsigned long long)mono << 6) | (unsigned)(63 - d);
        // branchless bubble insert into sorted-desc list
#pragma unroll
        for (int i = 0; i < TOPKK; ++i) {
            bool gt = key > list[i];
            unsigned long long mx = gt ? key : list[i];
            unsigned long long mn = gt ? list[i] : key;
            list[i] = mx; key = mn;
        }
    }
    int rowL = p * 64 + lane;
    if (hh == 1) {
#pragma unroll
        for (int i = 0; i < TOPKK; ++i) sK[rowL][i] = list[i];
    }
    __syncthreads();
    if (hh == 0) {
        // merge: top-12 of two sorted-desc 12-lists via half-cleaner (set-exact)
        unsigned long long M[TOPKK];
#pragma unroll
        for (int i = 0; i < TOPKK; ++i) {
            unsigned long long o = sK[rowL][11 - i];
            M[i] = (list[i] > o) ? list[i] : o;
        }
        // membership mask over inv-d; kpos = 11 - rank(inv-d ascending below mine)
        unsigned long long m = 0ull;
#pragma unroll
        for (int i = 0; i < TOPKK; ++i) m |= 1ull << (unsigned)(M[i] & 63ull);
#pragma unroll
        for (int i = 0; i < TOPKK; ++i) {
            unsigned a = (unsigned)(M[i] & 63ull);
            int kpos = 11 - __popcll(m & ((1ull << a) - 1ull));
            int d    = 63 - (int)a;
            atomicAdd(&counts[((size_t)b * TOPKK + kpos) * NSPA + d], 1);
        }
    }
}

// ---------------- output assembly ----------------
__global__ __launch_bounds__(256) void select_out(const float* __restrict__ x,
                                                  const int* __restrict__ counts,
                                                  float* __restrict__ out) {
    int row = blockIdx.x;
    int b = row / 14, k = row - b * 14;
    int d = threadIdx.x;
    if (k < 2) {
        out[(size_t)row * D_EMB + d]       = x[((size_t)(b * NTOK + k)) * D_EMB + d];
        out[(size_t)row * D_EMB + d + 256] = x[((size_t)(b * NTOK + k)) * D_EMB + d + 256];
    } else {
        int kk = k - 2;
        const int* cnt = counts + ((size_t)b * TOPKK + kk) * NSPA;
        __shared__ int sc[NSPA];
        if (d < NSPA) sc[d] = cnt[d];
        __syncthreads();
        float a0 = 0.f, a1 = 0.f;
        for (int l = 0; l < NSPA; ++l) {
            int c = sc[l];
            if (c) {
                float w = (float)c / 500.0f;
                const float* xr = x + ((size_t)(b * NTOK + 2 + l)) * D_EMB;
                a0 = fmaf(w, xr[d], a0);
                a1 = fmaf(w, xr[d + 256], a1);
            }
        }
        out[(size_t)row * D_EMB + d]       = a0;
        out[(size_t)row * D_EMB + d + 256] = a1;
    }
}

extern "C" void kernel_launch(void* const* d_in, const int* in_sizes, int n_in,
                              void* d_out, int out_size, void* d_ws, size_t ws_size,
                              hipStream_t stream) {
    const float* x    = (const float*)d_in[0];
    const float* ln_g = (const float*)d_in[1];
    const float* ln_b = (const float*)d_in[2];
    const float* w_in = (const float*)d_in[3];
    const float* wq   = (const float*)d_in[4];
    const float* wk   = (const float*)d_in[5];
    const float* wv   = (const float*)d_in[6];
    const float* wo   = (const float*)d_in[7];
    const float* w1   = (const float*)d_in[8];
    const float* w2   = (const float*)d_in[9];
    float* out = (float*)d_out;

    char* W = (char*)d_ws;
    short* xn_hi  = (short*)(W + 0);            // 9,830,400 B
    short* xn_lo  = (short*)(W + 9830400);      // 9,830,400 B
    //   region reuse after xn is dead:
    short* ao_hi  = (short*)(W + 0);            // 4,915,200
    short* ao_lo  = (short*)(W + 4915200);      // 4,915,200
    short* h2_hi  = (short*)(W + 9830400);      // 4,915,200
    short* h2_lo  = (short*)(W + 14745600);     // 4,915,200
    short* h1_hi  = (short*)(W + 19660800);     // 4,915,200
    short* h1_lo  = (short*)(W + 24576000);     // 4,915,200
    float* h3     = (float*)(W + 19660800);     // 9,830,400 (aliases h1 after qkv)
    float* q      = (float*)(W + 29491200);     // 9,830,400
    float* h2f    = (float*)(W + 29491200);     // aliases q after attn
    float* k      = (float*)(W + 39321600);     // 9,830,400
    float* v      = (float*)(W + 49152000);     // 9,830,400
    short* win_hi = (short*)(W + 58982400);     // 262,144
    short* win_lo = (short*)(W + 59244544);
    short* wq_hi  = (short*)(W + 59506688);     // 131,072 each from here
    short* wq_lo  = (short*)(W + 59637760);
    short* wk_hi  = (short*)(W + 59768832);
    short* wk_lo  = (short*)(W + 59899904);
    short* wv_hi  = (short*)(W + 60030976);
    short* wv_lo  = (short*)(W + 60162048);
    short* wo_hi  = (short*)(W + 60293120);
    short* wo_lo  = (short*)(W + 60424192);
    short* w1a_hi = (short*)(W + 60555264);
    short* w1a_lo = (short*)(W + 60686336);
    short* w1b_hi = (short*)(W + 60817408);
    short* w1b_lo = (short*)(W + 60948480);
    short* gm_hi  = (short*)(W + 61079552);     // 98,304
    short* gm_lo  = (short*)(W + 61177856);     // 98,304
    float* gw     = (float*)(W + 61276160);     // 196,608
    float* pred   = (float*)(W + 61472768);     // 38,400
    int*   counts = (int*)  (W + 61511168);     // 442,368

    // 0. counts zero-init moved off the critical path (independent of everything above topk)
    hipMemsetAsync(counts, 0, (size_t)B2 * TOPKK * NSPA * sizeof(int), stream);
    // 1. fused LN + weight swizzle
    prep_kernel<<<2656, 256, 0, stream>>>(x, ln_g, ln_b, xn_hi, xn_lo,
        w_in, wq, wk, wv, wo, w1,
        win_hi, win_lo, wq_hi, wq_lo, wk_hi, wk_lo, wv_hi, wv_lo,
        wo_hi, wo_lo, w1a_hi, w1a_lo, w1b_hi, w1b_lo);
    // 2. h1 = gelu(xn @ w_in)  (swizzled out only)
    gemm_one<16><<<dim3(150, 8), 256, 0, stream>>>((const short8*)xn_hi, (const short8*)xn_lo,
        (const short8*)win_hi, (const short8*)win_lo, nullptr, h1_hi, h1_lo, nullptr, 1);
    // 3. fused q/k/v = h1 @ w{q,k,v}
    gemm_qkv<<<dim3(150, 24), 256, 0, stream>>>((const short8*)h1_hi, (const short8*)h1_lo,
        (const short8*)wq_hi, (const short8*)wq_lo, (const short8*)wk_hi, (const short8*)wk_lo,
        (const short8*)wv_hi, (const short8*)wv_lo, q, k, v);
    // 4. attention -> swizzled ao (xn region now dead)
    attn_kernel<<<B2 * 2, 256, 0, stream>>>(q, k, v, ao_hi, ao_lo);
    // 5. h2 = ao @ wo  (fp32 into old q + swizzled)
    gemm_one<8><<<dim3(150, 8), 256, 0, stream>>>((const short8*)ao_hi, (const short8*)ao_lo,
        (const short8*)wo_hi, (const short8*)wo_lo, h2f, h2_hi, h2_lo, nullptr, 0);
    // 6. gmean (swizzled)
    mean50<<<B2, 256, 0, stream>>>(h2f, gm_hi, gm_lo);
    // 7. gw = gmean @ w1[256:]
    gemm_one<8><<<dim3(3, 8), 256, 0, stream>>>((const short8*)gm_hi, (const short8*)gm_lo,
        (const short8*)w1b_hi, (const short8*)w1b_lo, gw, nullptr, nullptr, nullptr, 0);
    // 8. h3 = gelu(h2 @ w1[:256] + gw-bias)
    gemm_one<8><<<dim3(150, 8), 256, 0, stream>>>((const short8*)h2_hi, (const short8*)h2_lo,
        (const short8*)w1a_hi, (const short8*)w1a_lo, h3, nullptr, nullptr, gw, 1);
    // 9. scores, topk, output
    matvec_tanh<<<ROWS / 4, 256, 0, stream>>>(h3, w2, pred);
    topk_kernel<<<750, 256, 0, stream>>>(pred, counts);
    select_out<<<B2 * 14, 256, 0, stream>>>(x, counts, out);
}

// Round 8
// 291.256 us; speedup vs baseline: 1.6055x; 1.0210x over previous
//
#include <hip/hip_runtime.h>
#include <stdint.h>

// ---------------- problem constants ----------------
#define B2      192          // 16 * MAX_FRAMES
#define NTOK    50           // tokens per frame-batch
#define ROWS    9600         // B2 * NTOK
#define D_EMB   512
#define C_DIM   256
#define HD      128          // head dim
#define NSAMP   500
#define TOPKK   12
#define NSPA    48           // 50 - SEL_DIM

typedef short short8 __attribute__((ext_vector_type(8)));
typedef float f32x4  __attribute__((ext_vector_type(4)));

__device__ __forceinline__ float gelu_f(float x) {
    return 0.5f * x * (1.0f + erff(x * 0.7071067811865476f));
}
__device__ __forceinline__ uint16_t f2bf(float x) {   // RNE fp32->bf16
    uint32_t u = __float_as_uint(x);
    return (uint16_t)((u + 0x7fffu + ((u >> 16) & 1u)) >> 16);
}
__device__ __forceinline__ float bf2f(uint16_t b) {
    return __uint_as_float(((uint32_t)b) << 16);
}
// swizzled A-operand halfword index (frag-contiguous MFMA layout)
__device__ __forceinline__ size_t swzA(int m, int k, int K) {
    return ((size_t)(m >> 4) * (K >> 5) + (k >> 5)) * 512
         + (size_t)((((k >> 3) & 3) * 16 + (m & 15)) * 8 + (k & 7));
}

// ---------------- fused LN + weight swizzle (one launch) ----------------
// blocks 0..2399: LayerNorm rows; blocks 2400..2655: weight swizzle.
__global__ __launch_bounds__(256) void prep_kernel(const float* __restrict__ x,
                                                   const float* __restrict__ g,
                                                   const float* __restrict__ b,
                                                   short* __restrict__ xh,
                                                   short* __restrict__ xl,
                                                   const float* __restrict__ w_in, const float* __restrict__ wq,
                                                   const float* __restrict__ wk, const float* __restrict__ wv,
                                                   const float* __restrict__ wo, const float* __restrict__ w1,
                                                   short* win_hi, short* win_lo, short* wq_hi, short* wq_lo,
                                                   short* wk_hi, short* wk_lo, short* wv_hi, short* wv_lo,
                                                   short* wo_hi, short* wo_lo, short* w1a_hi, short* w1a_lo,
                                                   short* w1b_hi, short* w1b_lo) {
    if (blockIdx.x < 2400) {
        int row  = blockIdx.x * 4 + (threadIdx.x >> 6);
        int lane = threadIdx.x & 63;
        const float* rp = x + (size_t)row * D_EMB;
        float4 v0 = *(const float4*)(rp + lane * 8);
        float4 v1 = *(const float4*)(rp + lane * 8 + 4);
        float s  = v0.x + v0.y + v0.z + v0.w + v1.x + v1.y + v1.z + v1.w;
        float s2 = v0.x*v0.x + v0.y*v0.y + v0.z*v0.z + v0.w*v0.w
                 + v1.x*v1.x + v1.y*v1.y + v1.z*v1.z + v1.w*v1.w;
#pragma unroll
        for (int off = 32; off; off >>= 1) {
            s  += __shfl_xor(s,  off);
            s2 += __shfl_xor(s2, off);
        }
        float mu  = s / 512.0f;
        float var = s2 / 512.0f - mu * mu;
        float inv = 1.0f / sqrtf(var + 1e-5f);
        const float* gp = g + lane * 8;
        const float* bp = b + lane * 8;
        float o[8];
        o[0]=(v0.x-mu)*inv*gp[0]+bp[0]; o[1]=(v0.y-mu)*inv*gp[1]+bp[1];
        o[2]=(v0.z-mu)*inv*gp[2]+bp[2]; o[3]=(v0.w-mu)*inv*gp[3]+bp[3];
        o[4]=(v1.x-mu)*inv*gp[4]+bp[4]; o[5]=(v1.y-mu)*inv*gp[5]+bp[5];
        o[6]=(v1.z-mu)*inv*gp[6]+bp[6]; o[7]=(v1.w-mu)*inv*gp[7]+bp[7];
        short8 h8, l8;
#pragma unroll
        for (int j = 0; j < 8; ++j) {
            uint16_t h = f2bf(o[j]);
            h8[j] = (short)h;
            l8[j] = (short)f2bf(o[j] - bf2f(h));
        }
        size_t blk = (size_t)(row >> 4) * 16 + (lane >> 2);
        int inner  = (lane & 3) * 16 + (row & 15);
        ((short8*)xh)[blk * 64 + inner] = h8;
        ((short8*)xl)[blk * 64 + inner] = l8;
    } else {
        int blk = blockIdx.x - 2400;
        const float* W; short *hi, *lo; int K, base;
        if      (blk <  64) { W = w_in;            hi = win_hi; lo = win_lo; K = 512; base = 0;   }
        else if (blk <  96) { W = wq;              hi = wq_hi;  lo = wq_lo;  K = 256; base = 64;  }
        else if (blk < 128) { W = wk;              hi = wk_hi;  lo = wk_lo;  K = 256; base = 96;  }
        else if (blk < 160) { W = wv;              hi = wv_hi;  lo = wv_lo;  K = 256; base = 128; }
        else if (blk < 192) { W = wo;              hi = wo_hi;  lo = wo_lo;  K = 256; base = 160; }
        else if (blk < 224) { W = w1;              hi = w1a_hi; lo = w1a_lo; K = 256; base = 192; }
        else                { W = w1 + 256 * 256;  hi = w1b_hi; lo = w1b_lo; K = 256; base = 224; }
        int t = (blk - base) * 256 + threadIdx.x;
        int n = t & 255, k8 = t >> 8;
        short8 h8, l8;
#pragma unroll
        for (int j = 0; j < 8; ++j) {
            float wvl = W[(size_t)(k8 * 8 + j) * 256 + n];
            uint16_t h = f2bf(wvl);
            h8[j] = (short)h;
            l8[j] = (short)f2bf(wvl - bf2f(h));
        }
        size_t bb = (size_t)(n >> 4) * (K >> 5) + (k8 >> 2);
        int inner = (k8 & 3) * 16 + (n & 15);
        ((short8*)hi)[bb * 64 + inner] = h8;
        ((short8*)lo)[bb * 64 + inner] = l8;
    }
}

// ---------------- split-bf16 MFMA core: 16x32 wave tile, depth-2 rolling prefetch ----------------
template<int KB>
__device__ __forceinline__ void mm_core(const short8* __restrict__ pAh, const short8* __restrict__ pAl,
                                        const short8* __restrict__ pBh0, const short8* __restrict__ pBl0,
                                        const short8* __restrict__ pBh1, const short8* __restrict__ pBl1,
                                        f32x4& acc0, f32x4& acc1) {
    short8 ah[3], al[3], bh0[3], bl0[3], bh1[3], bl1[3];
#pragma unroll
    for (int i = 0; i < 2; ++i) {
        int off = i * 64;
        ah[i] = pAh[off];  al[i] = pAl[off];
        bh0[i] = pBh0[off]; bl0[i] = pBl0[off];
        bh1[i] = pBh1[off]; bl1[i] = pBl1[off];
    }
#pragma unroll
    for (int ks = 0; ks < KB; ++ks) {
        int cur = ks % 3;
        if (ks + 2 < KB) {
            int pre = (ks + 2) % 3, off = (ks + 2) * 64;
            ah[pre] = pAh[off];  al[pre] = pAl[off];
            bh0[pre] = pBh0[off]; bl0[pre] = pBl0[off];
            bh1[pre] = pBh1[off]; bl1[pre] = pBl1[off];
        }
        acc0 = __builtin_amdgcn_mfma_f32_16x16x32_bf16(ah[cur], bh0[cur], acc0, 0, 0, 0);
        acc0 = __builtin_amdgcn_mfma_f32_16x16x32_bf16(ah[cur], bl0[cur], acc0, 0, 0, 0);
        acc0 = __builtin_amdgcn_mfma_f32_16x16x32_bf16(al[cur], bh0[cur], acc0, 0, 0, 0);
        acc1 = __builtin_amdgcn_mfma_f32_16x16x32_bf16(ah[cur], bh1[cur], acc1, 0, 0, 0);
        acc1 = __builtin_amdgcn_mfma_f32_16x16x32_bf16(ah[cur], bl1[cur], acc1, 0, 0, 0);
        acc1 = __builtin_amdgcn_mfma_f32_16x16x32_bf16(al[cur], bh1[cur], acc1, 0, 0, 0);
    }
}

__device__ __forceinline__ void epi_store(f32x4 acc, int row0, int col, int N,
                                          float* __restrict__ Cf, short* __restrict__ Chi,
                                          short* __restrict__ Clo,
                                          const float* __restrict__ bias, int act) {
#pragma unroll
    for (int r = 0; r < 4; ++r) {
        int row = row0 + r;
        float v2 = acc[r];
        if (bias) v2 += bias[(size_t)(row / 50) * N + col];
        if (act)  v2 = gelu_f(v2);
        if (Cf) Cf[(size_t)row * N + col] = v2;
        if (Chi) {
            uint16_t h = f2bf(v2);
            size_t ad = swzA(row, col, 256);
            Chi[ad] = (short)h;
            Clo[ad] = (short)f2bf(v2 - bf2f(h));
        }
    }
}

// single GEMM: grid (M/64, N/32); wave = 16 rows x 32 cols (2 n-strips)
template<int KB>
__global__ __launch_bounds__(256) void gemm_one(const short8* __restrict__ Ah,
                                                const short8* __restrict__ Al,
                                                const short8* __restrict__ Bh,
                                                const short8* __restrict__ Bl,
                                                float* __restrict__ Cf,
                                                short* __restrict__ Chi,
                                                short* __restrict__ Clo,
                                                const float* __restrict__ bias,
                                                int act) {
    int lane = threadIdx.x & 63;
    int wv   = threadIdx.x >> 6;
    int ms   = blockIdx.x * 4 + wv;
    int ns0  = blockIdx.y * 2;
    const short8* pAh  = Ah + (size_t)ms  * KB * 64 + lane;
    const short8* pAl  = Al + (size_t)ms  * KB * 64 + lane;
    const short8* pBh0 = Bh + (size_t)ns0 * KB * 64 + lane;
    const short8* pBl0 = Bl + (size_t)ns0 * KB * 64 + lane;
    const short8* pBh1 = pBh0 + (size_t)KB * 64;
    const short8* pBl1 = pBl0 + (size_t)KB * 64;
    f32x4 acc0 = {0.f,0.f,0.f,0.f}, acc1 = {0.f,0.f,0.f,0.f};
    mm_core<KB>(pAh, pAl, pBh0, pBl0, pBh1, pBl1, acc0, acc1);
    int row0 = ms * 16 + (lane >> 4) * 4;
    int cin  = lane & 15;
    epi_store(acc0, row0, ns0 * 16 + cin,      256, Cf, Chi, Clo, bias, act);
    epi_store(acc1, row0, (ns0 + 1) * 16 + cin, 256, Cf, Chi, Clo, bias, act);
}

// fused q/k/v: grid (150, 24); matrix = blockIdx.y>>3, n-strip-pair = blockIdx.y&7
__global__ __launch_bounds__(256) void gemm_qkv(const short8* __restrict__ Ah,
                                                const short8* __restrict__ Al,
                                                const short8* __restrict__ Bhq, const short8* __restrict__ Blq,
                                                const short8* __restrict__ Bhk, const short8* __restrict__ Blk,
                                                const short8* __restrict__ Bhv, const short8* __restrict__ Blv,
                                                float* __restrict__ q, float* __restrict__ k,
                                                float* __restrict__ v) {
    int lane = threadIdx.x & 63;
    int wv   = threadIdx.x >> 6;
    int ms   = blockIdx.x * 4 + wv;
    int sel  = blockIdx.y >> 3;
    int ns0  = (blockIdx.y & 7) * 2;
    const short8* Bh = (sel == 0) ? Bhq : (sel == 1) ? Bhk : Bhv;
    const short8* Bl = (sel == 0) ? Blq : (sel == 1) ? Blk : Blv;
    float* C = (sel == 0) ? q : (sel == 1) ? k : v;
    const short8* pAh  = Ah + (size_t)ms  * 8 * 64 + lane;
    const short8* pAl  = Al + (size_t)ms  * 8 * 64 + lane;
    const short8* pBh0 = Bh + (size_t)ns0 * 8 * 64 + lane;
    const short8* pBl0 = Bl + (size_t)ns0 * 8 * 64 + lane;
    const short8* pBh1 = pBh0 + 8 * 64;
    const short8* pBl1 = pBl0 + 8 * 64;
    f32x4 acc0 = {0.f,0.f,0.f,0.f}, acc1 = {0.f,0.f,0.f,0.f};
    mm_core<8>(pAh, pAl, pBh0, pBl0, pBh1, pBl1, acc0, acc1);
    int row0 = ms * 16 + (lane >> 4) * 4;
    int cin  = lane & 15;
    epi_store(acc0, row0, ns0 * 16 + cin,      256, C, nullptr, nullptr, nullptr, 0);
    epi_store(acc1, row0, (ns0 + 1) * 16 + cin, 256, C, nullptr, nullptr, nullptr, 0);
}

// ---------------- attention: one block per (batch, head); 2x2-blocked QK^T, float4 PV ----------------
__global__ __launch_bounds__(256) void attn_kernel(const float* __restrict__ q,
                                                   const float* __restrict__ k,
                                                   const float* __restrict__ v,
                                                   short* __restrict__ aoh,
                                                   short* __restrict__ aol) {
    __shared__ float sQ[NTOK * 132];
    __shared__ float sK[NTOK * 132];
    __shared__ float sS[NTOK * 51];
    int blk = blockIdx.x;
    int b = blk >> 1, h = blk & 1;
    const size_t base = (size_t)b * NTOK * C_DIM + h * HD;
    int tid = threadIdx.x;
    for (int idx = tid; idx < 1600; idx += 256) {
        int r = idx >> 5, c = (idx & 31) * 4;
        *(float4*)&sQ[r * 132 + c] = *(const float4*)(q + base + (size_t)r * C_DIM + c);
        *(float4*)&sK[r * 132 + c] = *(const float4*)(k + base + (size_t)r * C_DIM + c);
    }
    __syncthreads();
    for (int e = tid; e < 625; e += 256) {    // 25x25 quads of 2x2 dots
        int i2 = e / 25, j2 = e - i2 * 25;
        int i = i2 * 2, j = j2 * 2;
        const float* qi0 = &sQ[i * 132];
        const float* qi1 = qi0 + 132;
        const float* kj0 = &sK[j * 132];
        const float* kj1 = kj0 + 132;
        float4 a00 = {0,0,0,0}, a01 = {0,0,0,0}, a10 = {0,0,0,0}, a11 = {0,0,0,0};
#pragma unroll
        for (int t = 0; t < 32; ++t) {
            float4 q0 = *(const float4*)&qi0[t * 4];
            float4 q1 = *(const float4*)&qi1[t * 4];
            float4 b0 = *(const float4*)&kj0[t * 4];
            float4 b1 = *(const float4*)&kj1[t * 4];
            a00.x = fmaf(q0.x, b0.x, a00.x); a00.y = fmaf(q0.y, b0.y, a00.y);
            a00.z = fmaf(q0.z, b0.z, a00.z); a00.w = fmaf(q0.w, b0.w, a00.w);
            a01.x = fmaf(q0.x, b1.x, a01.x); a01.y = fmaf(q0.y, b1.y, a01.y);
            a01.z = fmaf(q0.z, b1.z, a01.z); a01.w = fmaf(q0.w, b1.w, a01.w);
            a10.x = fmaf(q1.x, b0.x, a10.x); a10.y = fmaf(q1.y, b0.y, a10.y);
            a10.z = fmaf(q1.z, b0.z, a10.z); a10.w = fmaf(q1.w, b0.w, a10.w);
            a11.x = fmaf(q1.x, b1.x, a11.x); a11.y = fmaf(q1.y, b1.y, a11.y);
            a11.z = fmaf(q1.z, b1.z, a11.z); a11.w = fmaf(q1.w, b1.w, a11.w);
        }
        const float sc = 0.08838834764831845f;   // 1/sqrt(128)
        sS[i * 51 + j]           = (a00.x + a00.y + a00.z + a00.w) * sc;
        sS[i * 51 + j + 1]       = (a01.x + a01.y + a01.z + a01.w) * sc;
        sS[(i + 1) * 51 + j]     = (a10.x + a10.y + a10.z + a10.w) * sc;
        sS[(i + 1) * 51 + j + 1] = (a11.x + a11.y + a11.z + a11.w) * sc;
    }
    __syncthreads();
    for (int idx = tid; idx < 1600; idx += 256) {   // overwrite sQ with v
        int r = idx >> 5, c = (idx & 31) * 4;
        *(float4*)&sQ[r * 132 + c] = *(const float4*)(v + base + (size_t)r * C_DIM + c);
    }
    if (tid < NTOK) {
        float* row = &sS[tid * 51];
        float m = row[0];
        for (int j = 1; j < NTOK; ++j) m = fmaxf(m, row[j]);
        float sum = 0.f;
        for (int j = 0; j < NTOK; ++j) { float e2 = expf(row[j] - m); row[j] = e2; sum += e2; }
        float inv = 1.0f / sum;
        for (int j = 0; j < NTOK; ++j) row[j] *= inv;
    }
    __syncthreads();
    for (int e = tid; e < 1600; e += 256) {   // PV: 4 d's per thread
        int i = e >> 5, d4 = (e & 31) * 4;
        const float* srow = &sS[i * 51];
        float4 acc = {0,0,0,0};
#pragma unroll
        for (int j = 0; j < NTOK; ++j) {
            float w = srow[j];
            float4 v4 = *(const float4*)&sQ[j * 132 + d4];
            acc.x = fmaf(w, v4.x, acc.x); acc.y = fmaf(w, v4.y, acc.y);
            acc.z = fmaf(w, v4.z, acc.z); acc.w = fmaf(w, v4.w, acc.w);
        }
        int row = b * NTOK + i;
        float vals[4] = {acc.x, acc.y, acc.z, acc.w};
#pragma unroll
        for (int c = 0; c < 4; ++c) {
            int col = h * HD + d4 + c;
            uint16_t hh = f2bf(vals[c]);
            size_t ad = swzA(row, col, 256);
            aoh[ad] = (short)hh;
            aol[ad] = (short)f2bf(vals[c] - bf2f(hh));
        }
    }
}

// ---------------- mean over 50 tokens -> swizzled hi/lo bf16 ----------------
__global__ __launch_bounds__(256) void mean50(const float* __restrict__ h2,
                                              short* __restrict__ gh,
                                              short* __restrict__ gl) {
    int b = blockIdx.x, c = threadIdx.x;
    float s = 0.f;
    for (int n = 0; n < NTOK; ++n) s += h2[((size_t)b * NTOK + n) * C_DIM + c];
    float g = s / 50.0f;
    uint16_t h = f2bf(g);
    size_t ad = swzA(b, c, 256);
    gh[ad] = (short)h;
    gl[ad] = (short)f2bf(g - bf2f(h));
}

// ---------------- pred = tanh(h3 @ w2): one wave per row ----------------
__global__ __launch_bounds__(256) void matvec_tanh(const float* __restrict__ h3,
                                                   const float* __restrict__ w2,
                                                   float* __restrict__ pred) {
    int row  = blockIdx.x * 4 + (threadIdx.x >> 6);
    int lane = threadIdx.x & 63;
    const float* rp = h3 + (size_t)row * C_DIM;
    float4 a = *(const float4*)(rp + lane * 4);
    float4 w = *(const float4*)(w2 + lane * 4);
    float s = a.x * w.x + a.y * w.y + a.z * w.z + a.w * w.w;
#pragma unroll
    for (int off = 32; off; off >>= 1) s += __shfl_xor(s, off);
    if (lane == 0) pred[row] = tanhf(s);
}

// ---------------- JAX threefry2x32 with key (0,1) ----------------
__device__ __forceinline__ uint32_t rotl32(uint32_t x, int r) {
    return (x << r) | (x >> (32 - r));
}
__device__ __forceinline__ void threefry01(uint32_t& x0, uint32_t& x1) {
    const uint32_t ks0 = 0u, ks1 = 1u, ks2 = 0x1BD11BDBu;
    x0 += ks0; x1 += ks1;
#define TFR(r) { x0 += x1; x1 = rotl32(x1, r); x1 ^= x0; }
    TFR(13) TFR(15) TFR(26) TFR(6)  x0 += ks1; x1 += ks2 + 1u;
    TFR(17) TFR(29) TFR(16) TFR(24) x0 += ks2; x1 += ks0 + 2u;
    TFR(13) TFR(15) TFR(26) TFR(6)  x0 += ks0; x1 += ks1 + 3u;
    TFR(17) TFR(29) TFR(16) TFR(24) x0 += ks1; x1 += ks2 + 4u;
    TFR(13) TFR(15) TFR(26) TFR(6)  x0 += ks2; x1 += ks0 + 5u;
#undef TFR
}

__device__ __forceinline__ float erfinv_xla(float x) {
    float w = -log1pf(-x * x);
    float p;
    if (w < 5.0f) {
        w -= 2.5f;
        p = 2.81022636e-08f;
        p = fmaf(p, w, 3.43273939e-07f);
        p = fmaf(p, w, -3.5233877e-06f);
        p = fmaf(p, w, -4.39150654e-06f);
        p = fmaf(p, w, 0.00021858087f);
        p = fmaf(p, w, -0.00125372503f);
        p = fmaf(p, w, -0.00417768164f);
        p = fmaf(p, w, 0.246640727f);
        p = fmaf(p, w, 1.50140941f);
    } else {
        w = sqrtf(w) - 3.0f;
        p = -0.000200214257f;
        p = fmaf(p, w, 0.000100950558f);
        p = fmaf(p, w, 0.00134934322f);
        p = fmaf(p, w, -0.00367342844f);
        p = fmaf(p, w, 0.00573950773f);
        p = fmaf(p, w, -0.0076224613f);
        p = fmaf(p, w, 0.00943887047f);
        p = fmaf(p, w, 1.00167406f);
        p = fmaf(p, w, 2.83297682f);
    }
    return p * x;
}

__device__ __forceinline__ float bits_to_normal(uint32_t bits) {
    float f = __uint_as_float((bits >> 9) | 0x3f800000u) - 1.0f;
    float u = f * 2.0f + (-0.99999994039535522461f);
    u = fmaxf(-0.99999994039535522461f, u);
    return 1.4142135623730951f * erfinv_xla(u);
}

// ---------------- topk, transposed: lane = sample, loop over 48 positions ----------------
// __launch_bounds__(256, 4): cap 4 waves/EU -> 128 VGPR budget so the 12-key
// sorted list (24 VGPRs) stays in registers. (R7: default budget spilled it to
// scratch -- VGPR=36, WRITE_SIZE=19 MB, 56 us.)
__global__ __launch_bounds__(256, 4) void topk_kernel(const float* __restrict__ pred,
                                                      int* __restrict__ counts) {
    __shared__ unsigned long long sK[128][13];   // partner half's 12 keys; +1 pad
    int lane = threadIdx.x & 63;
    int wv   = threadIdx.x >> 6;
    int p    = wv >> 1;          // wave-pair 0/1 -> 64 samples each
    int hh   = wv & 1;           // half: 0 -> d=0..23, 1 -> d=24..47
    int g    = blockIdx.x * 128 + p * 64 + lane; // global sample id 0..95999
    int b    = g / NSAMP;
    int s    = g - b * NSAMP;
    uint32_t base = (uint32_t)((b * NSAMP + s) * NSPA);
    const float* sp = pred + b * NTOK + 2;

    unsigned long long list[TOPKK];
#pragma unroll
    for (int i = 0; i < TOPKK; ++i) list[i] = 0ull;   // 0 < any real key

    int d0 = hh * 24;
    // first 12 elements: triangular insert (element dd needs only dd+1 steps)
#pragma unroll
    for (int dd = 0; dd < 12; ++dd) {
        int d = d0 + dd;
        uint32_t x0 = 0u, x1 = base + (uint32_t)d;
        threefry01(x0, x1);
        float n  = bits_to_normal(x0 ^ x1);
        float v  = sp[d] + n * 0.05f;
        uint32_t vb   = __float_as_uint(v);
        uint32_t mono = (vb & 0x80000000u) ? ~vb : (vb | 0x80000000u);
        unsigned long long key = ((unsigned long long)mono << 6) | (unsigned)(63 - d);
#pragma unroll
        for (int i = 0; i < TOPKK; ++i) {
            if (i <= dd) {
                bool gt = key > list[i];
                unsigned long long mx = gt ? key : list[i];
                unsigned long long mn = gt ? list[i] : key;
                list[i] = mx; key = mn;
            }
        }
    }
#pragma unroll 2
    for (int dd = 12; dd < 24; ++dd) {
        int d = d0 + dd;
        uint32_t x0 = 0u, x1 = base + (uint32_t)d;
        threefry01(x0, x1);
        float n  = bits_to_normal(x0 ^ x1);
        float v  = sp[d] + n * 0.05f;
        uint32_t vb   = __float_as_uint(v);
        uint32_t mono = (vb & 0x80000000u) ? ~vb : (vb | 0x80000000u);
        unsigned long long key = ((unsigned long long)mono << 6) | (unsigned)(63 - d);
#pragma unroll
        for (int i = 0; i < TOPKK; ++i) {
            bool gt = key > list[i];
            unsigned long long mx = gt ? key : list[i];
            unsigned long long mn = gt ? list[i] : key;
            list[i] = mx; key = mn;
        }
    }
    int rowL = p * 64 + lane;
    if (hh == 1) {
#pragma unroll
        for (int i = 0; i < TOPKK; ++i) sK[rowL][i] = list[i];
    }
    __syncthreads();
    if (hh == 0) {
        // merge: top-12 of two sorted-desc 12-lists via half-cleaner (set-exact)
        unsigned long long M[TOPKK];
#pragma unroll
        for (int i = 0; i < TOPKK; ++i) {
            unsigned long long o = sK[rowL][11 - i];
            M[i] = (list[i] > o) ? list[i] : o;
        }
        // membership mask over inv-d; kpos = 11 - rank(inv-d ascending below mine)
        unsigned long long m = 0ull;
#pragma unroll
        for (int i = 0; i < TOPKK; ++i) m |= 1ull << (unsigned)(M[i] & 63ull);
#pragma unroll
        for (int i = 0; i < TOPKK; ++i) {
            unsigned a = (unsigned)(M[i] & 63ull);
            int kpos = 11 - __popcll(m & ((1ull << a) - 1ull));
            int d    = 63 - (int)a;
            atomicAdd(&counts[((size_t)b * TOPKK + kpos) * NSPA + d], 1);
        }
    }
}

// ---------------- output assembly ----------------
__global__ __launch_bounds__(256) void select_out(const float* __restrict__ x,
                                                  const int* __restrict__ counts,
                                                  float* __restrict__ out) {
    int row = blockIdx.x;
    int b = row / 14, k = row - b * 14;
    int d = threadIdx.x;
    if (k < 2) {
        out[(size_t)row * D_EMB + d]       = x[((size_t)(b * NTOK + k)) * D_EMB + d];
        out[(size_t)row * D_EMB + d + 256] = x[((size_t)(b * NTOK + k)) * D_EMB + d + 256];
    } else {
        int kk = k - 2;
        const int* cnt = counts + ((size_t)b * TOPKK + kk) * NSPA;
        __shared__ int sc[NSPA];
        if (d < NSPA) sc[d] = cnt[d];
        __syncthreads();
        float a0 = 0.f, a1 = 0.f;
        for (int l = 0; l < NSPA; ++l) {
            int c = sc[l];
            if (c) {
                float w = (float)c / 500.0f;
                const float* xr = x + ((size_t)(b * NTOK + 2 + l)) * D_EMB;
                a0 = fmaf(w, xr[d], a0);
                a1 = fmaf(w, xr[d + 256], a1);
            }
        }
        out[(size_t)row * D_EMB + d]       = a0;
        out[(size_t)row * D_EMB + d + 256] = a1;
    }
}

extern "C" void kernel_launch(void* const* d_in, const int* in_sizes, int n_in,
                              void* d_out, int out_size, void* d_ws, size_t ws_size,
                              hipStream_t stream) {
    const float* x    = (const float*)d_in[0];
    const float* ln_g = (const float*)d_in[1];
    const float* ln_b = (const float*)d_in[2];
    const float* w_in = (const float*)d_in[3];
    const float* wq   = (const float*)d_in[4];
    const float* wk   = (const float*)d_in[5];
    const float* wv   = (const float*)d_in[6];
    const float* wo   = (const float*)d_in[7];
    const float* w1   = (const float*)d_in[8];
    const float* w2   = (const float*)d_in[9];
    float* out = (float*)d_out;

    char* W = (char*)d_ws;
    short* xn_hi  = (short*)(W + 0);            // 9,830,400 B
    short* xn_lo  = (short*)(W + 9830400);      // 9,830,400 B
    //   region reuse after xn is dead:
    short* ao_hi  = (short*)(W + 0);            // 4,915,200
    short* ao_lo  = (short*)(W + 4915200);      // 4,915,200
    short* h2_hi  = (short*)(W + 9830400);      // 4,915,200
    short* h2_lo  = (short*)(W + 14745600);     // 4,915,200
    short* h1_hi  = (short*)(W + 19660800);     // 4,915,200
    short* h1_lo  = (short*)(W + 24576000);     // 4,915,200
    float* h3     = (float*)(W + 19660800);     // 9,830,400 (aliases h1 after qkv)
    float* q      = (float*)(W + 29491200);     // 9,830,400
    float* h2f    = (float*)(W + 29491200);     // aliases q after attn
    float* k      = (float*)(W + 39321600);     // 9,830,400
    float* v      = (float*)(W + 49152000);     // 9,830,400
    short* win_hi = (short*)(W + 58982400);     // 262,144
    short* win_lo = (short*)(W + 59244544);
    short* wq_hi  = (short*)(W + 59506688);     // 131,072 each from here
    short* wq_lo  = (short*)(W + 59637760);
    short* wk_hi  = (short*)(W + 59768832);
    short* wk_lo  = (short*)(W + 59899904);
    short* wv_hi  = (short*)(W + 60030976);
    short* wv_lo  = (short*)(W + 60162048);
    short* wo_hi  = (short*)(W + 60293120);
    short* wo_lo  = (short*)(W + 60424192);
    short* w1a_hi = (short*)(W + 60555264);
    short* w1a_lo = (short*)(W + 60686336);
    short* w1b_hi = (short*)(W + 60817408);
    short* w1b_lo = (short*)(W + 60948480);
    short* gm_hi  = (short*)(W + 61079552);     // 98,304
    short* gm_lo  = (short*)(W + 61177856);     // 98,304
    float* gw     = (float*)(W + 61276160);     // 196,608
    float* pred   = (float*)(W + 61472768);     // 38,400
    int*   counts = (int*)  (W + 61511168);     // 442,368

    // 0. counts zero-init off the critical path
    hipMemsetAsync(counts, 0, (size_t)B2 * TOPKK * NSPA * sizeof(int), stream);
    // 1. fused LN + weight swizzle
    prep_kernel<<<2656, 256, 0, stream>>>(x, ln_g, ln_b, xn_hi, xn_lo,
        w_in, wq, wk, wv, wo, w1,
        win_hi, win_lo, wq_hi, wq_lo, wk_hi, wk_lo, wv_hi, wv_lo,
        wo_hi, wo_lo, w1a_hi, w1a_lo, w1b_hi, w1b_lo);
    // 2. h1 = gelu(xn @ w_in)  (swizzled out only)
    gemm_one<16><<<dim3(150, 8), 256, 0, stream>>>((const short8*)xn_hi, (const short8*)xn_lo,
        (const short8*)win_hi, (const short8*)win_lo, nullptr, h1_hi, h1_lo, nullptr, 1);
    // 3. fused q/k/v = h1 @ w{q,k,v}
    gemm_qkv<<<dim3(150, 24), 256, 0, stream>>>((const short8*)h1_hi, (const short8*)h1_lo,
        (const short8*)wq_hi, (const short8*)wq_lo, (const short8*)wk_hi, (const short8*)wk_lo,
        (const short8*)wv_hi, (const short8*)wv_lo, q, k, v);
    // 4. attention -> swizzled ao (xn region now dead)
    attn_kernel<<<B2 * 2, 256, 0, stream>>>(q, k, v, ao_hi, ao_lo);
    // 5. h2 = ao @ wo  (fp32 into old q + swizzled)
    gemm_one<8><<<dim3(150, 8), 256, 0, stream>>>((const short8*)ao_hi, (const short8*)ao_lo,
        (const short8*)wo_hi, (const short8*)wo_lo, h2f, h2_hi, h2_lo, nullptr, 0);
    // 6. gmean (swizzled)
    mean50<<<B2, 256, 0, stream>>>(h2f, gm_hi, gm_lo);
    // 7. gw = gmean @ w1[256:]
    gemm_one<8><<<dim3(3, 8), 256, 0, stream>>>((const short8*)gm_hi, (const short8*)gm_lo,
        (const short8*)w1b_hi, (const short8*)w1b_lo, gw, nullptr, nullptr, nullptr, 0);
    // 8. h3 = gelu(h2 @ w1[:256] + gw-bias)
    gemm_one<8><<<dim3(150, 8), 256, 0, stream>>>((const short8*)h2_hi, (const short8*)h2_lo,
        (const short8*)w1a_hi, (const short8*)w1a_lo, h3, nullptr, nullptr, gw, 1);
    // 9. scores, topk, output
    matvec_tanh<<<ROWS / 4, 256, 0, stream>>>(h3, w2, pred);
    topk_kernel<<<750, 256, 0, stream>>>(pred, counts);
    select_out<<<B2 * 14, 256, 0, stream>>>(x, counts, out);
}